// Round 1
// 24639.999 us; speedup vs baseline: 1.5081x; 1.5081x over previous
//
#include <hip/hip_runtime.h>
#include <math.h>

// Problem constants
#define B    64
#define T    512
#define D    1024
#define H    1024
#define E    128
#define OO   512

#define NBLK 256
#define NTHR 512

typedef _Float16 f16x8 __attribute__((ext_vector_type(8)));
typedef float    f32x4 __attribute__((ext_vector_type(4)));

// All MFMA inputs are scaled by 128 (f16 denormal floor dodge); gates get
// scaled back by 1/(128*128) at the cell update. Exact pow2 => no rounding.
#define SCALE      128.0f
#define INV_SCALE2 (1.0f / 16384.0f)

// ws byte layout (all 16B-aligned)
#define WS_HBUF   0          // fp32 [2][64][1024]   = 524288 B
#define WS_H16HI  524288     // f16  [2][64][1024]   = 262144 B (scaled x128)
#define WS_H16LO  786432     // f16  [2][64][1024]   = 262144 B
#define WS_E16HI  1048576    // f16  [513][128]      = 131328 B (row 512 = init_tensor)
#define WS_E16LO  1179904    // f16  [513][128]      = 131328 B
#define WS_AMAX   1311232    // u64, one entry per 64B line: idx=(parity*64+b)*8 -> 8192 B
#define WS_SYNC   1319424    // u32[576] sync words                              -> 2304 B
#define N_ZWORDS  ((8192 + 2304) / 4)   // amax + sync zero region, 2624 u32

// sync word indices (64B-padded lines)
#define SY_GCNT(g)  ((g) * 16)          // 16 groups, barrier arrivals
#define SY_DCNT(g)  (256 + (g) * 16)    // 16 groups, phase-B done arrivals
#define SY_GTOP     512
#define SY_GGEN     528
#define SY_DTOP     544
#define SY_DFLAG    560

__global__ __launch_bounds__(256) void init_kernel(
    float* hbuf0, _Float16* h16hi, _Float16* h16lo,
    _Float16* e16hi, _Float16* e16lo,
    const float* emb, const float* init_t, unsigned* zw) {
  const int i = blockIdx.x * 256 + threadIdx.x;  // 512 blocks -> 0..131071
  if (i < B * H) hbuf0[i] = 0.f;                 // h fp32 parity 0
  if (i < 2 * B * H) { h16hi[i] = (_Float16)0.f; h16lo[i] = (_Float16)0.f; }
  if (i < 513 * 128) {
    const int row = i >> 7, col = i & 127;
    const float v = ((row < 512) ? emb[i] : init_t[col]) * SCALE;
    const _Float16 h = (_Float16)v;
    e16hi[i] = h;
    e16lo[i] = (_Float16)(v - (float)h);
  }
  if (i < N_ZWORDS) zw[i] = 0u;                  // amax entries + all sync words
}

// Monotonic-count poll: RELAXED (bypasses caches via sc0/sc1, no invalidate)
// with periodic ACQUIRE fallback as a visibility safety net.
__device__ __forceinline__ void poll_ge(unsigned* p, unsigned want) {
  unsigned sp = 0;
  for (;;) {
    const unsigned g = ((++sp & 255u) == 0u)
        ? __hip_atomic_load(p, __ATOMIC_ACQUIRE, __HIP_MEMORY_SCOPE_AGENT)
        : __hip_atomic_load(p, __ATOMIC_RELAXED, __HIP_MEMORY_SCOPE_AGENT);
    if (g >= want) break;
    __builtin_amdgcn_s_sleep(1);
  }
}

// Device-wide barrier, hierarchical 16x16 arrival tree on padded lines.
// Arrivals are RELEASE (wb only); leaders ACQUIRE-load to chain visibility;
// waiters poll RELAXED and take ONE ACQUIRE load on exit.
__device__ __forceinline__ void gbar(unsigned* sync, int bid, unsigned q) {
  __syncthreads();
  if (threadIdx.x == 0) {
    unsigned* gc = &sync[SY_GCNT(bid >> 4)];
    const unsigned a = __hip_atomic_fetch_add(gc, 1u, __ATOMIC_RELEASE,
                                              __HIP_MEMORY_SCOPE_AGENT);
    if ((a & 15u) == 15u) {                       // last of my 16-group
      (void)__hip_atomic_load(gc, __ATOMIC_ACQUIRE, __HIP_MEMORY_SCOPE_AGENT);
      const unsigned b = __hip_atomic_fetch_add(&sync[SY_GTOP], 1u, __ATOMIC_RELEASE,
                                                __HIP_MEMORY_SCOPE_AGENT);
      if ((b & 15u) == 15u) {                     // last group
        (void)__hip_atomic_load(&sync[SY_GTOP], __ATOMIC_ACQUIRE,
                                __HIP_MEMORY_SCOPE_AGENT);
        __hip_atomic_store(&sync[SY_GGEN], q + 1u, __ATOMIC_RELEASE,
                           __HIP_MEMORY_SCOPE_AGENT);
      }
    }
    poll_ge(&sync[SY_GGEN], q + 1u);
    (void)__hip_atomic_load(&sync[SY_GGEN], __ATOMIC_ACQUIRE,
                            __HIP_MEMORY_SCOPE_AGENT);
  }
  __syncthreads();
}

__device__ __forceinline__ float sigm(float x) { return 1.f / (1.f + expf(-x)); }

// fp32[8] -> scaled f16 hi/lo split
__device__ __forceinline__ void cvt8(const float* v, f16x8& hi, f16x8& lo) {
  #pragma unroll
  for (int j = 0; j < 8; ++j) {
    const float s = v[j] * SCALE;
    const _Float16 h = (_Float16)s;
    hi[j] = h;
    lo[j] = (_Float16)(s - (float)h);
  }
}

__global__ __launch_bounds__(NTHR, 2) void decode_kernel(
    const float* __restrict__ enc, const int* __restrict__ seq_lens,
    const float* __restrict__ W_ih, const float* __restrict__ W_hh,
    const float* __restrict__ b_ih, const float* __restrict__ b_hh,
    const float* __restrict__ W_lin, const float* __restrict__ b_lin,
    float* __restrict__ out, float* __restrict__ hbuf,
    _Float16* __restrict__ h16hi, _Float16* __restrict__ h16lo,
    const _Float16* __restrict__ e16hi, const _Float16* __restrict__ e16lo,
    unsigned long long* __restrict__ amax, unsigned* __restrict__ sync) {

  // LDS: per-wave MFMA partials gp[8 waves][16 m][64 b pad 66] + logit stash
  __shared__ float gp[8 * 16 * 66];   // 33792 B
  __shared__ float lstash[136];

  const int tid  = threadIdx.x;
  const int lane = tid & 63;
  const int wv   = tid >> 6;          // 0..7
  const int bid  = blockIdx.x;
  const int l15  = lane & 15;
  const int lq   = lane >> 4;         // quad 0..3

  // ---- MFMA identity: block owns 16 gate-rows (m = g*4+mi <-> r = g*H + bid*4+mi)
  const int am   = l15;               // A-fragment row for this lane
  const int arow = (am >> 2) * H + bid * 4 + (am & 3);
  // wave k-slice: waves 0..3 own 9 k-tiles, 4..7 own 8 (68 total, K=2176)
  const int ktbase  = (wv < 4) ? wv * 9 : 36 + (wv - 4) * 8;
  const int ntk     = (wv < 4) ? 9 : 8;
  // wave 7 owns kt 60..67: h-tiles 60..63 run in the main loop; emb tiles
  // 64..67 (the only argmax-dependent work on the device) run in its tail.
  const int ntk_pre = (wv == 7) ? 4 : ntk;

  // ---- prologue: W -> scaled f16 hi/lo A-fragments, resident all 512 steps ----
  f16x8 ahi[9], alo[9];
  #pragma unroll
  for (int i = 0; i < 9; ++i) {
    if (i < ntk) {
      const int kg = (ktbase + i) * 32 + lq * 8;   // 0..2175, 8-aligned
      float wv8[8];
      const float* src;
      if (kg < 1024)       src = W_ih + (size_t)arow * (D + E) + kg;
      else if (kg < 2048)  src = W_hh + (size_t)arow * H + (kg - 1024);
      else                 src = W_ih + (size_t)arow * (D + E) + D + (kg - 2048);
      *(float4*)(wv8)     = *(const float4*)(src);
      *(float4*)(wv8 + 4) = *(const float4*)(src + 4);
      cvt8(wv8, ahi[i], alo[i]);
    } else {
      ahi[i] = (f16x8)(_Float16)0.f; alo[i] = (f16x8)(_Float16)0.f;
    }
  }

  // ---- cell-update identity: tid<256 owns (cmi, cb) ----
  const int cb  = tid & 63;
  const int cmi = tid >> 6;                        // valid when tid < 256
  const int csl = seq_lens[cb];
  float bias[4];
  if (tid < 256) {
    #pragma unroll
    for (int g = 0; g < 4; ++g) {
      const int r = g * H + bid * 4 + cmi;
      bias[g] = b_ih[r] + b_hh[r];
    }
  }

  // ---- phase B identity ----
  const int bq = bid >> 5, og = bid & 31;
  const int kp = lane & 7;
  const int pb_b  = bq * 8 + (lane >> 3);
  const int pb_sl = seq_lens[pb_b];
  const int o0 = og * 16 + wv * 2, o1 = o0 + 1;
  const float bl0 = b_lin[o0], bl1 = b_lin[o1];

  // ---- wave-7 private feedback state (replaces per-step A-pre + idxbuf LDS) ----
  int ebidx[4] = {-1, -1, -1, -1};
  int sl7[4];
  #pragma unroll
  for (int nt = 0; nt < 4; ++nt) sl7[nt] = seq_lens[nt * 16 + l15];

  float c_reg = 0.f, h_reg = 0.f;

  for (int t = 0; t < T; ++t) {
    // ---------- phase A: gates via MFMA, 3-product f16 hi/lo split ----------
    const int par0 = t & 1;
    f32x4 acc[4] = {{0.f,0.f,0.f,0.f},{0.f,0.f,0.f,0.f},
                    {0.f,0.f,0.f,0.f},{0.f,0.f,0.f,0.f}};
    #pragma unroll
    for (int nt = 0; nt < 4; ++nt) {
      const int bb = nt * 16 + l15;            // B-frag batch (column n)
      const float*    xrow = enc + ((size_t)bb * T + t) * D;
      const _Float16* hhi  = h16hi + (size_t)par0 * (B * H) + (size_t)bb * H;
      const _Float16* hlo  = h16lo + (size_t)par0 * (B * H) + (size_t)bb * H;
      #pragma unroll
      for (int i = 0; i < 9; ++i) {
        if (i < ntk_pre) {
          const int kt = ktbase + i;
          const int kg = kt * 32 + lq * 8;
          f16x8 bhi, blo;
          if (kt < 32) {                       // x region: fp32 -> on-the-fly split
            float xv[8];
            *(float4*)(xv)     = *(const float4*)(xrow + kg);
            *(float4*)(xv + 4) = *(const float4*)(xrow + kg + 4);
            cvt8(xv, bhi, blo);
          } else {                             // h region: pre-split f16
            bhi = *(const f16x8*)(hhi + (kg - 1024));
            blo = *(const f16x8*)(hlo + (kg - 1024));
          }
          acc[nt] = __builtin_amdgcn_mfma_f32_16x16x32_f16(ahi[i], bhi, acc[nt], 0, 0, 0);
          acc[nt] = __builtin_amdgcn_mfma_f32_16x16x32_f16(alo[i], bhi, acc[nt], 0, 0, 0);
          acc[nt] = __builtin_amdgcn_mfma_f32_16x16x32_f16(ahi[i], blo, acc[nt], 0, 0, 0);
        }
      }
    }

    // ---------- wave-7 tail: argmax flag wait + emb contribution ----------
    if (wv == 7) {
      if (t > 0) {
        poll_ge(&sync[SY_DFLAG], (unsigned)t);   // phase B of t-1 done device-wide
        (void)__hip_atomic_load(&sync[SY_DFLAG], __ATOMIC_ACQUIRE,
                                __HIP_MEMORY_SCOPE_AGENT);
        const int slot = (t - 1) & 1;
        #pragma unroll
        for (int nt = 0; nt < 4; ++nt) {
          if ((t - 1) < sl7[nt]) {
            const unsigned long long p = __hip_atomic_load(
                &amax[(size_t)(slot * 64 + nt * 16 + l15) * 8],
                __ATOMIC_RELAXED, __HIP_MEMORY_SCOPE_AGENT);
            ebidx[nt] = 511 - (int)(unsigned)(p & 0xffffffffu);
          }
        }
      }
      #pragma unroll
      for (int nt = 0; nt < 4; ++nt) {
        const size_t ebase = (size_t)((ebidx[nt] < 0) ? 512 : ebidx[nt]) * 128;
        #pragma unroll
        for (int i = 4; i < 8; ++i) {          // kt = 64..67
          const int eo = (i - 4) * 32 + lq * 8;
          f16x8 bhi = *(const f16x8*)(e16hi + ebase + eo);
          f16x8 blo = *(const f16x8*)(e16lo + ebase + eo);
          acc[nt] = __builtin_amdgcn_mfma_f32_16x16x32_f16(ahi[i], bhi, acc[nt], 0, 0, 0);
          acc[nt] = __builtin_amdgcn_mfma_f32_16x16x32_f16(alo[i], bhi, acc[nt], 0, 0, 0);
          acc[nt] = __builtin_amdgcn_mfma_f32_16x16x32_f16(ahi[i], blo, acc[nt], 0, 0, 0);
        }
      }
    }

    // C-layout: col b = nt*16 + (lane&15), row m = quad*4 + reg
    {
      const int prow = lq * 4;
      #pragma unroll
      for (int nt = 0; nt < 4; ++nt) {
        const int pb = nt * 16 + l15;
        #pragma unroll
        for (int r = 0; r < 4; ++r)
          gp[(wv * 16 + prow + r) * 66 + pb] = acc[nt][r];
      }
    }
    __syncthreads();

    // ---------- cell update: sum 8 wave-partials, LSTM math (fp32) ----------
    if (tid < 256) {
      float g4[4];
      #pragma unroll
      for (int g = 0; g < 4; ++g) {
        float s = 0.f;
        #pragma unroll
        for (int w = 0; w < 8; ++w) s += gp[(w * 16 + g * 4 + cmi) * 66 + cb];
        g4[g] = s * INV_SCALE2 + bias[g];
      }
      const float xi = sigm(g4[0]), xf = sigm(g4[1]);
      const float xg = tanhf(g4[2]), xo = sigm(g4[3]);
      const float cn = xf * c_reg + xi * xg;
      const float hn = xo * tanhf(cn);
      if (t < csl) { c_reg = cn; h_reg = hn; }
      const int par1 = (t + 1) & 1;
      const size_t hoff = (size_t)par1 * (B * H) + (size_t)cb * H + (bid * 4 + cmi);
      hbuf[hoff] = h_reg;
      const float hs = h_reg * SCALE;
      const _Float16 hh = (_Float16)hs;
      h16hi[hoff] = hh;
      h16lo[hoff] = (_Float16)(hs - (float)hh);
    }

    gbar(sync, bid, (unsigned)t);  // the ONLY device barrier per step: h_t visible

    // ---------- phase B: exact fp32 logits + argmax ----------
    float f0 = 0.f, f1 = 0.f;
    const float* hr  = hbuf + (size_t)((t + 1) & 1) * (B * H) + (size_t)pb_b * H + kp * 4;
    const float* wl0 = W_lin + (size_t)o0 * H + kp * 4;
    const float* wl1 = W_lin + (size_t)o1 * H + kp * 4;
    #pragma unroll 4
    for (int j = 0; j < 32; ++j) {
      float4 h4 = *(const float4*)(hr + j * 32);
      float4 a4 = *(const float4*)(wl0 + j * 32);
      float4 c4 = *(const float4*)(wl1 + j * 32);
      f0 = fmaf(a4.x, h4.x, f0); f0 = fmaf(a4.y, h4.y, f0);
      f0 = fmaf(a4.z, h4.z, f0); f0 = fmaf(a4.w, h4.w, f0);
      f1 = fmaf(c4.x, h4.x, f1); f1 = fmaf(c4.y, h4.y, f1);
      f1 = fmaf(c4.z, h4.z, f1); f1 = fmaf(c4.w, h4.w, f1);
    }
    f0 += __shfl_xor(f0, 1, 64); f0 += __shfl_xor(f0, 2, 64); f0 += __shfl_xor(f0, 4, 64);
    f1 += __shfl_xor(f1, 1, 64); f1 += __shfl_xor(f1, 2, 64); f1 += __shfl_xor(f1, 4, 64);
    const float l0 = f0 + bl0, l1 = f1 + bl1;

    if (kp == 0) {
      const int boo = lane >> 3;
      lstash[boo * 17 + wv * 2]     = (t < pb_sl) ? l0 : 0.f;
      lstash[boo * 17 + wv * 2 + 1] = (t < pb_sl) ? l1 : 0.f;
      unsigned k0 = __float_as_uint(l0);
      k0 = (k0 & 0x80000000u) ? ~k0 : (k0 | 0x80000000u);
      unsigned k1 = __float_as_uint(l1);
      k1 = (k1 & 0x80000000u) ? ~k1 : (k1 | 0x80000000u);
      unsigned long long p0 = ((unsigned long long)k0 << 32) | (unsigned long long)(511 - o0);
      unsigned long long p1 = ((unsigned long long)k1 << 32) | (unsigned long long)(511 - o1);
      // reuse gp head as per-wave argmax scratch (safe: gp consumed pre-gbar;
      // next P1 overwrite of these floats is by wave 0 only, after its reads)
      ((unsigned long long*)gp)[wv * 8 + boo] = (p0 > p1) ? p0 : p1;
    }
    __syncthreads();
    if (tid < 8) {
      unsigned long long m = ((unsigned long long*)gp)[tid];
      #pragma unroll
      for (int w = 1; w < 8; ++w) {
        unsigned long long v = ((unsigned long long*)gp)[w * 8 + tid];
        m = (v > m) ? v : m;
      }
      // reset the OTHER slot (read by all wave-7s at P1 of this step, which
      // provably precedes this point via gbar(t)); next written at t+2.
      if (og == 0)
        __hip_atomic_store(&amax[(size_t)((((t + 1) & 1) * 64) + bq * 8 + tid) * 8],
                           0ull, __ATOMIC_RELAXED, __HIP_MEMORY_SCOPE_AGENT);
      __hip_atomic_fetch_max(&amax[(size_t)(((t & 1) * 64) + bq * 8 + tid) * 8], m,
                             __ATOMIC_RELAXED, __HIP_MEMORY_SCOPE_AGENT);
    }
    if (tid == 0) {
      // done-count chain -> dflag = t+1 (consumed only by wave-7s at t+1)
      unsigned* dc = &sync[SY_DCNT(bid >> 4)];
      const unsigned a = __hip_atomic_fetch_add(dc, 1u, __ATOMIC_RELEASE,
                                                __HIP_MEMORY_SCOPE_AGENT);
      if ((a & 15u) == 15u) {
        (void)__hip_atomic_load(dc, __ATOMIC_ACQUIRE, __HIP_MEMORY_SCOPE_AGENT);
        const unsigned b = __hip_atomic_fetch_add(&sync[SY_DTOP], 1u, __ATOMIC_RELEASE,
                                                  __HIP_MEMORY_SCOPE_AGENT);
        if ((b & 15u) == 15u) {
          (void)__hip_atomic_load(&sync[SY_DTOP], __ATOMIC_ACQUIRE,
                                  __HIP_MEMORY_SCOPE_AGENT);
          __hip_atomic_store(&sync[SY_DFLAG], (unsigned)(t + 1), __ATOMIC_RELEASE,
                             __HIP_MEMORY_SCOPE_AGENT);
        }
      }
    }
    if (tid < 128) {
      const int bb = tid >> 4, oj = tid & 15;
      out[((size_t)(bq * 8 + bb) * T + t) * OO + og * 16 + oj] = lstash[bb * 17 + oj];
    }
    // no second device barrier: loop back to P1 (h_t already synced by gbar(t))
  }
}

extern "C" void kernel_launch(void* const* d_in, const int* in_sizes, int n_in,
                              void* d_out, int out_size, void* d_ws, size_t ws_size,
                              hipStream_t stream) {
  (void)in_sizes; (void)n_in; (void)out_size; (void)ws_size;
  const float* enc    = (const float*)d_in[0];
  const int*   slen   = (const int*)d_in[1];
  const float* W_ih   = (const float*)d_in[2];
  const float* W_hh   = (const float*)d_in[3];
  const float* b_ih   = (const float*)d_in[4];
  const float* b_hh   = (const float*)d_in[5];
  const float* W_lin  = (const float*)d_in[6];
  const float* b_lin  = (const float*)d_in[7];
  const float* emb    = (const float*)d_in[8];
  const float* init_t = (const float*)d_in[9];
  float* out = (float*)d_out;

  char* ws = (char*)d_ws;
  float*     hbuf  = (float*)(ws + WS_HBUF);
  _Float16*  h16hi = (_Float16*)(ws + WS_H16HI);
  _Float16*  h16lo = (_Float16*)(ws + WS_H16LO);
  _Float16*  e16hi = (_Float16*)(ws + WS_E16HI);
  _Float16*  e16lo = (_Float16*)(ws + WS_E16LO);
  unsigned long long* amax = (unsigned long long*)(ws + WS_AMAX);
  unsigned*  sync  = (unsigned*)(ws + WS_SYNC);
  unsigned*  zw    = (unsigned*)(ws + WS_AMAX);   // zero amax+sync region

  hipLaunchKernelGGL(init_kernel, dim3(512), dim3(256), 0, stream,
                     hbuf, h16hi, h16lo, e16hi, e16lo, emb, init_t, zw);
  hipLaunchKernelGGL(decode_kernel, dim3(NBLK), dim3(NTHR), 0, stream,
                     enc, slen, W_ih, W_hh, b_ih, b_hh, W_lin, b_lin,
                     out, hbuf, h16hi, h16lo, e16hi, e16lo, amax, sync);
}

// Round 2
// 21650.186 us; speedup vs baseline: 1.7163x; 1.1381x over previous
//
#include <hip/hip_runtime.h>
#include <math.h>

// Problem constants
#define B    64
#define T    512
#define D    1024
#define H    1024
#define E    128
#define OO   512

#define NBLK 256
#define NTHR 512

typedef _Float16 f16x8 __attribute__((ext_vector_type(8)));
typedef _Float16 f16x4 __attribute__((ext_vector_type(4)));
typedef float    f32x4 __attribute__((ext_vector_type(4)));

// All MFMA inputs are scaled by 128 (f16 denormal floor dodge); gates get
// scaled back by 1/(128*128) at the cell update. Exact pow2 => no rounding.
#define SCALE      128.0f
#define INV_SCALE2 (1.0f / 16384.0f)

// ws byte layout (all 16B-aligned)
#define WS_HBUF   0          // fp32 [2][64][1024]   = 524288 B
#define WS_H16HI  524288     // f16  [2][64][1024]   = 262144 B (scaled x128)
#define WS_H16LO  786432     // f16  [2][64][1024]   = 262144 B
#define WS_E16HI  1048576    // f16  [513][128]      = 131328 B (row 512 = init_tensor)
#define WS_E16LO  1179904    // f16  [513][128]      = 131328 B
#define WS_AMAX   1311232    // u64, one entry per 64B line: idx=(parity*64+b)*8 -> 8192 B
#define WS_SYNC   1319424    // u32[576] sync words                              -> 2304 B
#define N_ZWORDS  ((8192 + 2304) / 4)   // amax + sync zero region, 2624 u32

// sync word indices (64B-padded lines)
#define SY_GCNT(g)  ((g) * 16)          // 16 groups, barrier arrivals
#define SY_DCNT(g)  (256 + (g) * 16)    // 16 groups, phase-B done arrivals
#define SY_GTOP     512
#define SY_GGEN     528
#define SY_DTOP     544
#define SY_DFLAG    560

#define SCOPE_AGT __HIP_MEMORY_SCOPE_AGENT

// Coherent (sc1, LLC-direct) helpers — relaxed agent atomics carry the sc
// bits that bypass the non-coherent per-XCD L2, with NO wbl2/inv microcode.
__device__ __forceinline__ unsigned long long ld8_coh(const void* p) {
  return __hip_atomic_load((const unsigned long long*)p, __ATOMIC_RELAXED, SCOPE_AGT);
}
__device__ __forceinline__ void st4f_coh(float* p, float v) {
  __hip_atomic_store(p, v, __ATOMIC_RELAXED, SCOPE_AGT);
}
__device__ __forceinline__ void st2h_coh(_Float16* p, _Float16 v) {
  union { _Float16 f; unsigned short u; } c; c.f = v;
  __hip_atomic_store((unsigned short*)p, c.u, __ATOMIC_RELAXED, SCOPE_AGT);
}

__global__ __launch_bounds__(256) void init_kernel(
    float* hbuf0, _Float16* h16hi, _Float16* h16lo,
    _Float16* e16hi, _Float16* e16lo,
    const float* emb, const float* init_t, unsigned* zw) {
  const int i = blockIdx.x * 256 + threadIdx.x;  // 512 blocks -> 0..131071
  if (i < B * H) hbuf0[i] = 0.f;                 // h fp32 parity 0
  if (i < 2 * B * H) { h16hi[i] = (_Float16)0.f; h16lo[i] = (_Float16)0.f; }
  if (i < 513 * 128) {
    const int row = i >> 7, col = i & 127;
    const float v = ((row < 512) ? emb[i] : init_t[col]) * SCALE;
    const _Float16 h = (_Float16)v;
    e16hi[i] = h;
    e16lo[i] = (_Float16)(v - (float)h);
  }
  if (i < N_ZWORDS) zw[i] = 0u;                  // amax entries + all sync words
}

// Pure-relaxed poll: sc1 loads read the LLC directly every time, so a
// relaxed poll is guaranteed to observe the flag; no acquire needed.
__device__ __forceinline__ void poll_ge(unsigned* p, unsigned want) {
  for (;;) {
    const unsigned g = __hip_atomic_load(p, __ATOMIC_RELAXED, SCOPE_AGT);
    if (g >= want) break;
    __builtin_amdgcn_s_sleep(1);
  }
  asm volatile("" ::: "memory");   // compiler fence: no hoisting past the poll
}

// Device-wide barrier, hierarchical 16x16 arrival tree, fence-free.
// Correctness: every wave's sc1 data stores retire vmcnt (=> LLC-visible)
// before s_barrier (explicit s_waitcnt + compiler's own drain); the relaxed
// arrival RMWs then chain at the LLC by data dependence; pollers read LLC.
__device__ __forceinline__ void gbar(unsigned* sync, int bid, unsigned q) {
  asm volatile("s_waitcnt vmcnt(0)" ::: "memory");  // my sc1 stores are at LLC
  __syncthreads();
  if (threadIdx.x == 0) {
    unsigned* gc = &sync[SY_GCNT(bid >> 4)];
    const unsigned a = __hip_atomic_fetch_add(gc, 1u, __ATOMIC_RELAXED, SCOPE_AGT);
    if ((a & 15u) == 15u) {                       // last of my 16-group
      const unsigned b = __hip_atomic_fetch_add(&sync[SY_GTOP], 1u,
                                                __ATOMIC_RELAXED, SCOPE_AGT);
      if ((b & 15u) == 15u)                       // last group
        __hip_atomic_store(&sync[SY_GGEN], q + 1u, __ATOMIC_RELAXED, SCOPE_AGT);
    }
    poll_ge(&sync[SY_GGEN], q + 1u);
  }
  __syncthreads();
}

__device__ __forceinline__ float sigm(float x) { return 1.f / (1.f + expf(-x)); }

// fp32[8] -> scaled f16 hi/lo split
__device__ __forceinline__ void cvt8(const float* v, f16x8& hi, f16x8& lo) {
  #pragma unroll
  for (int j = 0; j < 8; ++j) {
    const float s = v[j] * SCALE;
    const _Float16 h = (_Float16)s;
    hi[j] = h;
    lo[j] = (_Float16)(s - (float)h);
  }
}

__global__ __launch_bounds__(NTHR, 2) void decode_kernel(
    const float* __restrict__ enc, const int* __restrict__ seq_lens,
    const float* __restrict__ W_ih, const float* __restrict__ W_hh,
    const float* __restrict__ b_ih, const float* __restrict__ b_hh,
    const float* __restrict__ W_lin, const float* __restrict__ b_lin,
    float* __restrict__ out, float* __restrict__ hbuf,
    _Float16* __restrict__ h16hi, _Float16* __restrict__ h16lo,
    const _Float16* __restrict__ e16hi, const _Float16* __restrict__ e16lo,
    unsigned long long* __restrict__ amax, unsigned* __restrict__ sync) {

  // LDS: per-wave MFMA partials gp[8 waves][16 m][64 b pad 66] + logit stash
  __shared__ float gp[8 * 16 * 66];   // 33792 B
  __shared__ float lstash[136];

  const int tid  = threadIdx.x;
  const int lane = tid & 63;
  const int wv   = tid >> 6;          // 0..7
  const int bid  = blockIdx.x;
  const int l15  = lane & 15;
  const int lq   = lane >> 4;         // quad 0..3

  // ---- MFMA identity: block owns 16 gate-rows (m = g*4+mi <-> r = g*H + bid*4+mi)
  const int am   = l15;               // A-fragment row for this lane
  const int arow = (am >> 2) * H + bid * 4 + (am & 3);
  // wave k-slice: waves 0..3 own 9 k-tiles, 4..7 own 8 (68 total, K=2176)
  const int ktbase  = (wv < 4) ? wv * 9 : 36 + (wv - 4) * 8;
  const int ntk     = (wv < 4) ? 9 : 8;
  // wave 7 owns kt 60..67: h-tiles 60..63 run in the main loop; emb tiles
  // 64..67 (the only argmax-dependent work on the device) run in its tail.
  const int ntk_pre = (wv == 7) ? 4 : ntk;

  // ---- prologue: W -> scaled f16 hi/lo A-fragments, resident all 512 steps ----
  f16x8 ahi[9], alo[9];
  #pragma unroll
  for (int i = 0; i < 9; ++i) {
    if (i < ntk) {
      const int kg = (ktbase + i) * 32 + lq * 8;   // 0..2175, 8-aligned
      float wv8[8];
      const float* src;
      if (kg < 1024)       src = W_ih + (size_t)arow * (D + E) + kg;
      else if (kg < 2048)  src = W_hh + (size_t)arow * H + (kg - 1024);
      else                 src = W_ih + (size_t)arow * (D + E) + D + (kg - 2048);
      *(float4*)(wv8)     = *(const float4*)(src);
      *(float4*)(wv8 + 4) = *(const float4*)(src + 4);
      cvt8(wv8, ahi[i], alo[i]);
    } else {
      ahi[i] = (f16x8)(_Float16)0.f; alo[i] = (f16x8)(_Float16)0.f;
    }
  }

  // ---- cell-update identity: tid<256 owns (cmi, cb) ----
  const int cb  = tid & 63;
  const int cmi = tid >> 6;                        // valid when tid < 256
  const int csl = seq_lens[cb];
  float bias[4];
  if (tid < 256) {
    #pragma unroll
    for (int g = 0; g < 4; ++g) {
      const int r = g * H + bid * 4 + cmi;
      bias[g] = b_ih[r] + b_hh[r];
    }
  }

  // ---- phase B identity ----
  const int bq = bid >> 5, og = bid & 31;
  const int kp = lane & 7;
  const int pb_b  = bq * 8 + (lane >> 3);
  const int pb_sl = seq_lens[pb_b];
  const int o0 = og * 16 + wv * 2, o1 = o0 + 1;
  const float bl0 = b_lin[o0], bl1 = b_lin[o1];

  // ---- wave-7 private feedback state ----
  int ebidx[4] = {-1, -1, -1, -1};
  int sl7[4];
  #pragma unroll
  for (int nt = 0; nt < 4; ++nt) sl7[nt] = seq_lens[nt * 16 + l15];

  float c_reg = 0.f, h_reg = 0.f;

  for (int t = 0; t < T; ++t) {
    // ---------- phase A: gates via MFMA, 3-product f16 hi/lo split ----------
    const int par0 = t & 1;
    f32x4 acc[4] = {{0.f,0.f,0.f,0.f},{0.f,0.f,0.f,0.f},
                    {0.f,0.f,0.f,0.f},{0.f,0.f,0.f,0.f}};
    #pragma unroll
    for (int nt = 0; nt < 4; ++nt) {
      const int bb = nt * 16 + l15;            // B-frag batch (column n)
      const float*    xrow = enc + ((size_t)bb * T + t) * D;
      const _Float16* hhi  = h16hi + (size_t)par0 * (B * H) + (size_t)bb * H;
      const _Float16* hlo  = h16lo + (size_t)par0 * (B * H) + (size_t)bb * H;
      #pragma unroll
      for (int i = 0; i < 9; ++i) {
        if (i < ntk_pre) {
          const int kt = ktbase + i;
          const int kg = kt * 32 + lq * 8;
          f16x8 bhi, blo;
          if (kt < 32) {                       // x region: fp32 -> on-the-fly split
            float xv[8];
            *(float4*)(xv)     = *(const float4*)(xrow + kg);
            *(float4*)(xv + 4) = *(const float4*)(xrow + kg + 4);
            cvt8(xv, bhi, blo);
          } else {                             // h region: coherent (sc1) f16 loads
            const _Float16* ph = hhi + (kg - 1024);
            const _Float16* pl = hlo + (kg - 1024);
            union { unsigned long long u; f16x4 h; } h0, h1, l0, l1;
            h0.u = ld8_coh(ph);
            h1.u = ld8_coh(ph + 4);
            l0.u = ld8_coh(pl);
            l1.u = ld8_coh(pl + 4);
            bhi = __builtin_shufflevector(h0.h, h1.h, 0,1,2,3,4,5,6,7);
            blo = __builtin_shufflevector(l0.h, l1.h, 0,1,2,3,4,5,6,7);
          }
          acc[nt] = __builtin_amdgcn_mfma_f32_16x16x32_f16(ahi[i], bhi, acc[nt], 0, 0, 0);
          acc[nt] = __builtin_amdgcn_mfma_f32_16x16x32_f16(alo[i], bhi, acc[nt], 0, 0, 0);
          acc[nt] = __builtin_amdgcn_mfma_f32_16x16x32_f16(ahi[i], blo, acc[nt], 0, 0, 0);
        }
      }
    }

    // ---------- wave-7 tail: argmax flag wait + emb contribution ----------
    if (wv == 7) {
      if (t > 0) {
        if (lane == 0) poll_ge(&sync[SY_DFLAG], (unsigned)t);  // whole wave stalls w/ lane 0
        asm volatile("" ::: "memory");
        const int slot = (t - 1) & 1;
        #pragma unroll
        for (int nt = 0; nt < 4; ++nt) {
          if ((t - 1) < sl7[nt]) {
            const unsigned long long p = __hip_atomic_load(
                &amax[(size_t)(slot * 64 + nt * 16 + l15) * 8],
                __ATOMIC_RELAXED, SCOPE_AGT);
            ebidx[nt] = 511 - (int)(unsigned)(p & 0xffffffffu);
          }
        }
      }
      #pragma unroll
      for (int nt = 0; nt < 4; ++nt) {
        const size_t ebase = (size_t)((ebidx[nt] < 0) ? 512 : ebidx[nt]) * 128;
        #pragma unroll
        for (int i = 4; i < 8; ++i) {          // kt = 64..67
          const int eo = (i - 4) * 32 + lq * 8;
          f16x8 bhi = *(const f16x8*)(e16hi + ebase + eo);
          f16x8 blo = *(const f16x8*)(e16lo + ebase + eo);
          acc[nt] = __builtin_amdgcn_mfma_f32_16x16x32_f16(ahi[i], bhi, acc[nt], 0, 0, 0);
          acc[nt] = __builtin_amdgcn_mfma_f32_16x16x32_f16(alo[i], bhi, acc[nt], 0, 0, 0);
          acc[nt] = __builtin_amdgcn_mfma_f32_16x16x32_f16(ahi[i], blo, acc[nt], 0, 0, 0);
        }
      }
    }

    // C-layout: col b = nt*16 + (lane&15), row m = quad*4 + reg
    {
      const int prow = lq * 4;
      #pragma unroll
      for (int nt = 0; nt < 4; ++nt) {
        const int pb = nt * 16 + l15;
        #pragma unroll
        for (int r = 0; r < 4; ++r)
          gp[(wv * 16 + prow + r) * 66 + pb] = acc[nt][r];
      }
    }
    __syncthreads();

    // ---------- cell update: sum 8 wave-partials, LSTM math (fp32) ----------
    if (tid < 256) {
      float g4[4];
      #pragma unroll
      for (int g = 0; g < 4; ++g) {
        float s = 0.f;
        #pragma unroll
        for (int w = 0; w < 8; ++w) s += gp[(w * 16 + g * 4 + cmi) * 66 + cb];
        g4[g] = s * INV_SCALE2 + bias[g];
      }
      const float xi = sigm(g4[0]), xf = sigm(g4[1]);
      const float xg = tanhf(g4[2]), xo = sigm(g4[3]);
      const float cn = xf * c_reg + xi * xg;
      const float hn = xo * tanhf(cn);
      if (t < csl) { c_reg = cn; h_reg = hn; }
      const int par1 = (t + 1) & 1;
      const size_t hoff = (size_t)par1 * (B * H) + (size_t)cb * H + (bid * 4 + cmi);
      st4f_coh(&hbuf[hoff], h_reg);
      const float hs = h_reg * SCALE;
      const _Float16 hh = (_Float16)hs;
      st2h_coh(&h16hi[hoff], hh);
      st2h_coh(&h16lo[hoff], (_Float16)(hs - (float)hh));
    }

    gbar(sync, bid, (unsigned)t);  // the ONLY device barrier per step: h_t visible

    // ---------- phase B: exact fp32 logits + argmax ----------
    float f0 = 0.f, f1 = 0.f;
    const float* hr  = hbuf + (size_t)((t + 1) & 1) * (B * H) + (size_t)pb_b * H + kp * 4;
    const float* wl0 = W_lin + (size_t)o0 * H + kp * 4;
    const float* wl1 = W_lin + (size_t)o1 * H + kp * 4;
    #pragma unroll 4
    for (int j = 0; j < 32; ++j) {
      union { unsigned long long u; float f[2]; } ha, hb;
      ha.u = ld8_coh(hr + j * 32);           // coherent h (fresh at LLC)
      hb.u = ld8_coh(hr + j * 32 + 2);
      float4 a4 = *(const float4*)(wl0 + j * 32);   // W_lin: plain cached, L2-resident
      float4 c4 = *(const float4*)(wl1 + j * 32);
      f0 = fmaf(a4.x, ha.f[0], f0); f0 = fmaf(a4.y, ha.f[1], f0);
      f0 = fmaf(a4.z, hb.f[0], f0); f0 = fmaf(a4.w, hb.f[1], f0);
      f1 = fmaf(c4.x, ha.f[0], f1); f1 = fmaf(c4.y, ha.f[1], f1);
      f1 = fmaf(c4.z, hb.f[0], f1); f1 = fmaf(c4.w, hb.f[1], f1);
    }
    f0 += __shfl_xor(f0, 1, 64); f0 += __shfl_xor(f0, 2, 64); f0 += __shfl_xor(f0, 4, 64);
    f1 += __shfl_xor(f1, 1, 64); f1 += __shfl_xor(f1, 2, 64); f1 += __shfl_xor(f1, 4, 64);
    const float l0 = f0 + bl0, l1 = f1 + bl1;

    if (kp == 0) {
      const int boo = lane >> 3;
      lstash[boo * 17 + wv * 2]     = (t < pb_sl) ? l0 : 0.f;
      lstash[boo * 17 + wv * 2 + 1] = (t < pb_sl) ? l1 : 0.f;
      unsigned k0 = __float_as_uint(l0);
      k0 = (k0 & 0x80000000u) ? ~k0 : (k0 | 0x80000000u);
      unsigned k1 = __float_as_uint(l1);
      k1 = (k1 & 0x80000000u) ? ~k1 : (k1 | 0x80000000u);
      unsigned long long p0 = ((unsigned long long)k0 << 32) | (unsigned long long)(511 - o0);
      unsigned long long p1 = ((unsigned long long)k1 << 32) | (unsigned long long)(511 - o1);
      // reuse gp head as per-wave argmax scratch (safe: gp consumed pre-gbar)
      ((unsigned long long*)gp)[wv * 8 + boo] = (p0 > p1) ? p0 : p1;
    }
    __syncthreads();
    if (tid < 8) {
      unsigned long long m = ((unsigned long long*)gp)[tid];
      #pragma unroll
      for (int w = 1; w < 8; ++w) {
        unsigned long long v = ((unsigned long long*)gp)[w * 8 + tid];
        m = (v > m) ? v : m;
      }
      // reset the OTHER slot (read by all wave-7s at P1 of this step, which
      // provably precedes this point via gbar(t)); next written at t+2.
      if (og == 0)
        __hip_atomic_store(&amax[(size_t)((((t + 1) & 1) * 64) + bq * 8 + tid) * 8],
                           0ull, __ATOMIC_RELAXED, SCOPE_AGT);
      __hip_atomic_fetch_max(&amax[(size_t)(((t & 1) * 64) + bq * 8 + tid) * 8], m,
                             __ATOMIC_RELAXED, SCOPE_AGT);
    }
    if (tid == 0) {
      // wave 0: amax RMWs above are in THIS wave's vmcnt; drain, then count.
      asm volatile("s_waitcnt vmcnt(0)" ::: "memory");
      unsigned* dc = &sync[SY_DCNT(bid >> 4)];
      const unsigned a = __hip_atomic_fetch_add(dc, 1u, __ATOMIC_RELAXED, SCOPE_AGT);
      if ((a & 15u) == 15u) {
        const unsigned b = __hip_atomic_fetch_add(&sync[SY_DTOP], 1u,
                                                  __ATOMIC_RELAXED, SCOPE_AGT);
        if ((b & 15u) == 15u)
          __hip_atomic_store(&sync[SY_DFLAG], (unsigned)(t + 1),
                             __ATOMIC_RELAXED, SCOPE_AGT);
      }
    }
    if (tid < 128) {
      const int bb = tid >> 4, oj = tid & 15;
      out[((size_t)(bq * 8 + bb) * T + t) * OO + og * 16 + oj] = lstash[bb * 17 + oj];
    }
    // no second device barrier: loop back to P1 (h_t already synced by gbar(t))
  }
}

extern "C" void kernel_launch(void* const* d_in, const int* in_sizes, int n_in,
                              void* d_out, int out_size, void* d_ws, size_t ws_size,
                              hipStream_t stream) {
  (void)in_sizes; (void)n_in; (void)out_size; (void)ws_size;
  const float* enc    = (const float*)d_in[0];
  const int*   slen   = (const int*)d_in[1];
  const float* W_ih   = (const float*)d_in[2];
  const float* W_hh   = (const float*)d_in[3];
  const float* b_ih   = (const float*)d_in[4];
  const float* b_hh   = (const float*)d_in[5];
  const float* W_lin  = (const float*)d_in[6];
  const float* b_lin  = (const float*)d_in[7];
  const float* emb    = (const float*)d_in[8];
  const float* init_t = (const float*)d_in[9];
  float* out = (float*)d_out;

  char* ws = (char*)d_ws;
  float*     hbuf  = (float*)(ws + WS_HBUF);
  _Float16*  h16hi = (_Float16*)(ws + WS_H16HI);
  _Float16*  h16lo = (_Float16*)(ws + WS_H16LO);
  _Float16*  e16hi = (_Float16*)(ws + WS_E16HI);
  _Float16*  e16lo = (_Float16*)(ws + WS_E16LO);
  unsigned long long* amax = (unsigned long long*)(ws + WS_AMAX);
  unsigned*  sync  = (unsigned*)(ws + WS_SYNC);
  unsigned*  zw    = (unsigned*)(ws + WS_AMAX);   // zero amax+sync region

  hipLaunchKernelGGL(init_kernel, dim3(512), dim3(256), 0, stream,
                     hbuf, h16hi, h16lo, e16hi, e16lo, emb, init_t, zw);
  hipLaunchKernelGGL(decode_kernel, dim3(NBLK), dim3(NTHR), 0, stream,
                     enc, slen, W_ih, W_hh, b_ih, b_hh, W_lin, b_lin,
                     out, hbuf, h16hi, h16lo, e16hi, e16lo, amax, sync);
}

// Round 3
// 19798.828 us; speedup vs baseline: 1.8768x; 1.0935x over previous
//
#include <hip/hip_runtime.h>
#include <math.h>

// Problem constants
#define B    64
#define T    512
#define D    1024
#define H    1024
#define E    128
#define OO   512

#define NBLK 256
#define NTHR 512

typedef _Float16 f16x8 __attribute__((ext_vector_type(8)));
typedef _Float16 f16x4 __attribute__((ext_vector_type(4)));
typedef float    f32x4 __attribute__((ext_vector_type(4)));

// All MFMA inputs are scaled by 128 (f16 denormal floor dodge); gates get
// scaled back by 1/(128*128) at the cell update. Exact pow2 => no rounding.
#define SCALE      128.0f
#define INV_SCALE2 (1.0f / 16384.0f)

// ws byte layout (all 16B-aligned)
#define WS_HBUF   0          // fp32 [2][64][1024]   = 524288 B
#define WS_H16HI  524288     // f16  [2][64][1024]   = 262144 B (scaled x128)
#define WS_H16LO  786432     // f16  [2][64][1024]   = 262144 B
#define WS_E16HI  1048576    // f16  [513][128]      = 131328 B (row 512 = init_tensor)
#define WS_E16LO  1179904    // f16  [513][128]      = 131328 B
#define WS_AMAX   1311232    // u64, one entry per 64B line: idx=(parity*64+b)*8 -> 8192 B
#define WS_SYNC   1319424    // u32[576] sync words                              -> 2304 B
#define N_ZWORDS  ((8192 + 2304) / 4)   // amax + sync zero region, 2624 u32

// sync word indices (64B-padded lines)
#define SY_GCNT(g)  ((g) * 16)          // 16 groups, barrier arrivals
#define SY_DCNT(g)  (256 + (g) * 16)    // 16 groups, phase-B done arrivals
#define SY_GTOP     512
#define SY_GGEN     528
#define SY_DTOP     544
#define SY_DFLAG    560

#define SCOPE_AGT __HIP_MEMORY_SCOPE_AGENT

// Coherent (sc1, LLC-direct) helpers — relaxed agent atomics bypass the
// non-coherent per-XCD L2 with NO wbl2/inv microcode. Used ONLY for the
// producer side (h stores, out) and tiny sync/argmax words. Bulk consumer
// reads use plain cached loads made coherent by one buffer_inv per step.
__device__ __forceinline__ void st4f_coh(float* p, float v) {
  __hip_atomic_store(p, v, __ATOMIC_RELAXED, SCOPE_AGT);
}
__device__ __forceinline__ void st2h_coh(_Float16* p, _Float16 v) {
  union { _Float16 f; unsigned short u; } c; c.f = v;
  __hip_atomic_store((unsigned short*)p, c.u, __ATOMIC_RELAXED, SCOPE_AGT);
}

__global__ __launch_bounds__(256) void init_kernel(
    float* hbuf0, _Float16* h16hi, _Float16* h16lo,
    _Float16* e16hi, _Float16* e16lo,
    const float* emb, const float* init_t, unsigned* zw) {
  const int i = blockIdx.x * 256 + threadIdx.x;  // 512 blocks -> 0..131071
  if (i < B * H) hbuf0[i] = 0.f;                 // h fp32 parity 0
  if (i < 2 * B * H) { h16hi[i] = (_Float16)0.f; h16lo[i] = (_Float16)0.f; }
  if (i < 513 * 128) {
    const int row = i >> 7, col = i & 127;
    const float v = ((row < 512) ? emb[i] : init_t[col]) * SCALE;
    const _Float16 h = (_Float16)v;
    e16hi[i] = h;
    e16lo[i] = (_Float16)(v - (float)h);
  }
  if (i < N_ZWORDS) zw[i] = 0u;                  // amax entries + all sync words
}

// Pure-relaxed poll: sc1 loads read the LLC directly every time, so a
// relaxed poll is guaranteed to observe the flag; no acquire needed.
__device__ __forceinline__ void poll_ge(unsigned* p, unsigned want) {
  for (;;) {
    const unsigned g = __hip_atomic_load(p, __ATOMIC_RELAXED, SCOPE_AGT);
    if (g >= want) break;
    __builtin_amdgcn_s_sleep(1);
  }
  asm volatile("" ::: "memory");   // compiler fence: no hoisting past the poll
}

// Device-wide barrier + single cache-invalidate.
// Release: every wave drains vmcnt (its sc1 stores are LLC-visible), then
// relaxed arrival tree. Acquire: after the flag, tid0 issues ONE
// buffer_inv sc0 sc1 (L1+L2) and waits its completion (vmcnt-tracked);
// __syncthreads orders all waves' subsequent loads after it. Safe because
// no kernel store ever dirties L2 (all global stores are sc1 write-through).
__device__ __forceinline__ void gbar(unsigned* sync, int bid, unsigned q) {
  asm volatile("s_waitcnt vmcnt(0)" ::: "memory");  // my sc1 stores are at LLC
  __syncthreads();
  if (threadIdx.x == 0) {
    unsigned* gc = &sync[SY_GCNT(bid >> 4)];
    const unsigned a = __hip_atomic_fetch_add(gc, 1u, __ATOMIC_RELAXED, SCOPE_AGT);
    if ((a & 15u) == 15u) {                       // last of my 16-group
      const unsigned b = __hip_atomic_fetch_add(&sync[SY_GTOP], 1u,
                                                __ATOMIC_RELAXED, SCOPE_AGT);
      if ((b & 15u) == 15u)                       // last group
        __hip_atomic_store(&sync[SY_GGEN], q + 1u, __ATOMIC_RELAXED, SCOPE_AGT);
    }
    poll_ge(&sync[SY_GGEN], q + 1u);
    // one L1+L2 invalidate per block per step; complete before barrier exit
    asm volatile("buffer_inv sc0 sc1\n\ts_waitcnt vmcnt(0)" ::: "memory");
  }
  __syncthreads();
}

__device__ __forceinline__ float sigm(float x) { return 1.f / (1.f + expf(-x)); }

// fp32[8] -> scaled f16 hi/lo split
__device__ __forceinline__ void cvt8(const float* v, f16x8& hi, f16x8& lo) {
  #pragma unroll
  for (int j = 0; j < 8; ++j) {
    const float s = v[j] * SCALE;
    const _Float16 h = (_Float16)s;
    hi[j] = h;
    lo[j] = (_Float16)(s - (float)h);
  }
}

__global__ __launch_bounds__(NTHR, 2) void decode_kernel(
    const float* __restrict__ enc, const int* __restrict__ seq_lens,
    const float* __restrict__ W_ih, const float* __restrict__ W_hh,
    const float* __restrict__ b_ih, const float* __restrict__ b_hh,
    const float* __restrict__ W_lin, const float* __restrict__ b_lin,
    float* __restrict__ out, float* __restrict__ hbuf,
    _Float16* __restrict__ h16hi, _Float16* __restrict__ h16lo,
    const _Float16* __restrict__ e16hi, const _Float16* __restrict__ e16lo,
    unsigned long long* __restrict__ amax, unsigned* __restrict__ sync) {

  // LDS: per-wave MFMA partials gp[8 waves][16 m][64 b pad 66] + logit stash
  __shared__ float gp[8 * 16 * 66];   // 33792 B
  __shared__ float lstash[136];

  const int tid  = threadIdx.x;
  const int lane = tid & 63;
  const int wv   = tid >> 6;          // 0..7
  const int bid  = blockIdx.x;
  const int l15  = lane & 15;
  const int lq   = lane >> 4;         // quad 0..3

  // ---- MFMA identity: block owns 16 gate-rows (m = g*4+mi <-> r = g*H + bid*4+mi)
  const int am   = l15;               // A-fragment row for this lane
  const int arow = (am >> 2) * H + bid * 4 + (am & 3);
  // wave k-slice: waves 0..3 own 9 k-tiles, 4..7 own 8 (68 total, K=2176)
  const int ktbase  = (wv < 4) ? wv * 9 : 36 + (wv - 4) * 8;
  const int ntk     = (wv < 4) ? 9 : 8;
  // wave 7 owns kt 60..67: h-tiles 60..63 run in the main loop; emb tiles
  // 64..67 (the only argmax-dependent work on the device) run in its tail.
  const int ntk_pre = (wv == 7) ? 4 : ntk;

  // ---- prologue: W -> scaled f16 hi/lo A-fragments, resident all 512 steps ----
  f16x8 ahi[9], alo[9];
  #pragma unroll
  for (int i = 0; i < 9; ++i) {
    if (i < ntk) {
      const int kg = (ktbase + i) * 32 + lq * 8;   // 0..2175, 8-aligned
      float wv8[8];
      const float* src;
      if (kg < 1024)       src = W_ih + (size_t)arow * (D + E) + kg;
      else if (kg < 2048)  src = W_hh + (size_t)arow * H + (kg - 1024);
      else                 src = W_ih + (size_t)arow * (D + E) + D + (kg - 2048);
      *(float4*)(wv8)     = *(const float4*)(src);
      *(float4*)(wv8 + 4) = *(const float4*)(src + 4);
      cvt8(wv8, ahi[i], alo[i]);
    } else {
      ahi[i] = (f16x8)(_Float16)0.f; alo[i] = (f16x8)(_Float16)0.f;
    }
  }

  // ---- cell-update identity: tid<256 owns (cmi, cb) ----
  const int cb  = tid & 63;
  const int cmi = tid >> 6;                        // valid when tid < 256
  const int csl = seq_lens[cb];
  float bias[4];
  if (tid < 256) {
    #pragma unroll
    for (int g = 0; g < 4; ++g) {
      const int r = g * H + bid * 4 + cmi;
      bias[g] = b_ih[r] + b_hh[r];
    }
  }

  // ---- phase B identity ----
  const int bq = bid >> 5, og = bid & 31;
  const int kp = lane & 7;
  const int pb_b  = bq * 8 + (lane >> 3);
  const int pb_sl = seq_lens[pb_b];
  const int o0 = og * 16 + wv * 2, o1 = o0 + 1;
  const float bl0 = b_lin[o0], bl1 = b_lin[o1];

  // ---- wave-7 private feedback state ----
  int ebidx[4] = {-1, -1, -1, -1};
  int sl7[4];
  #pragma unroll
  for (int nt = 0; nt < 4; ++nt) sl7[nt] = seq_lens[nt * 16 + l15];

  float c_reg = 0.f, h_reg = 0.f;

  for (int t = 0; t < T; ++t) {
    // ---------- phase A: gates via MFMA, 3-product f16 hi/lo split ----------
    const int par0 = t & 1;
    f32x4 acc[4] = {{0.f,0.f,0.f,0.f},{0.f,0.f,0.f,0.f},
                    {0.f,0.f,0.f,0.f},{0.f,0.f,0.f,0.f}};
    #pragma unroll
    for (int nt = 0; nt < 4; ++nt) {
      const int bb = nt * 16 + l15;            // B-frag batch (column n)
      const float*    xrow = enc + ((size_t)bb * T + t) * D;
      const _Float16* hhi  = h16hi + (size_t)par0 * (B * H) + (size_t)bb * H;
      const _Float16* hlo  = h16lo + (size_t)par0 * (B * H) + (size_t)bb * H;
      #pragma unroll
      for (int i = 0; i < 9; ++i) {
        if (i < ntk_pre) {
          const int kt = ktbase + i;
          const int kg = kt * 32 + lq * 8;
          f16x8 bhi, blo;
          if (kt < 32) {                       // x region: fp32 -> on-the-fly split
            float xv[8];
            *(float4*)(xv)     = *(const float4*)(xrow + kg);
            *(float4*)(xv + 4) = *(const float4*)(xrow + kg + 4);
            cvt8(xv, bhi, blo);
          } else {                             // h region: plain cached loads
            bhi = *(const f16x8*)(hhi + (kg - 1024));   // fresh: post-inv L2
            blo = *(const f16x8*)(hlo + (kg - 1024));
          }
          acc[nt] = __builtin_amdgcn_mfma_f32_16x16x32_f16(ahi[i], bhi, acc[nt], 0, 0, 0);
          acc[nt] = __builtin_amdgcn_mfma_f32_16x16x32_f16(alo[i], bhi, acc[nt], 0, 0, 0);
          acc[nt] = __builtin_amdgcn_mfma_f32_16x16x32_f16(ahi[i], blo, acc[nt], 0, 0, 0);
        }
      }
    }

    // ---------- wave-7 tail: argmax flag wait + emb contribution ----------
    if (wv == 7) {
      if (t > 0) {
        if (lane == 0) poll_ge(&sync[SY_DFLAG], (unsigned)t);  // wave stalls w/ lane 0
        asm volatile("" ::: "memory");
        const int slot = (t - 1) & 1;
        #pragma unroll
        for (int nt = 0; nt < 4; ++nt) {
          if ((t - 1) < sl7[nt]) {
            const unsigned long long p = __hip_atomic_load(
                &amax[(size_t)(slot * 64 + nt * 16 + l15) * 8],
                __ATOMIC_RELAXED, SCOPE_AGT);
            ebidx[nt] = 511 - (int)(unsigned)(p & 0xffffffffu);
          }
        }
      }
      #pragma unroll
      for (int nt = 0; nt < 4; ++nt) {
        const size_t ebase = (size_t)((ebidx[nt] < 0) ? 512 : ebidx[nt]) * 128;
        #pragma unroll
        for (int i = 4; i < 8; ++i) {          // kt = 64..67
          const int eo = (i - 4) * 32 + lq * 8;
          f16x8 bhi = *(const f16x8*)(e16hi + ebase + eo);
          f16x8 blo = *(const f16x8*)(e16lo + ebase + eo);
          acc[nt] = __builtin_amdgcn_mfma_f32_16x16x32_f16(ahi[i], bhi, acc[nt], 0, 0, 0);
          acc[nt] = __builtin_amdgcn_mfma_f32_16x16x32_f16(alo[i], bhi, acc[nt], 0, 0, 0);
          acc[nt] = __builtin_amdgcn_mfma_f32_16x16x32_f16(ahi[i], blo, acc[nt], 0, 0, 0);
        }
      }
    }

    // C-layout: col b = nt*16 + (lane&15), row m = quad*4 + reg
    {
      const int prow = lq * 4;
      #pragma unroll
      for (int nt = 0; nt < 4; ++nt) {
        const int pb = nt * 16 + l15;
        #pragma unroll
        for (int r = 0; r < 4; ++r)
          gp[(wv * 16 + prow + r) * 66 + pb] = acc[nt][r];
      }
    }
    __syncthreads();

    // ---------- cell update: sum 8 wave-partials, LSTM math (fp32) ----------
    if (tid < 256) {
      float g4[4];
      #pragma unroll
      for (int g = 0; g < 4; ++g) {
        float s = 0.f;
        #pragma unroll
        for (int w = 0; w < 8; ++w) s += gp[(w * 16 + g * 4 + cmi) * 66 + cb];
        g4[g] = s * INV_SCALE2 + bias[g];
      }
      const float xi = sigm(g4[0]), xf = sigm(g4[1]);
      const float xg = tanhf(g4[2]), xo = sigm(g4[3]);
      const float cn = xf * c_reg + xi * xg;
      const float hn = xo * tanhf(cn);
      if (t < csl) { c_reg = cn; h_reg = hn; }
      const int par1 = (t + 1) & 1;
      const size_t hoff = (size_t)par1 * (B * H) + (size_t)cb * H + (bid * 4 + cmi);
      st4f_coh(&hbuf[hoff], h_reg);              // sc1: LLC write-through
      const float hs = h_reg * SCALE;
      const _Float16 hh = (_Float16)hs;
      st2h_coh(&h16hi[hoff], hh);
      st2h_coh(&h16lo[hoff], (_Float16)(hs - (float)hh));
    }

    gbar(sync, bid, (unsigned)t);  // device barrier + ONE L1/L2 inv: h_t coherent

    // ---------- phase B: exact fp32 logits + argmax (plain cached loads) ----------
    float f0 = 0.f, f1 = 0.f;
    const float* hr  = hbuf + (size_t)((t + 1) & 1) * (B * H) + (size_t)pb_b * H + kp * 4;
    const float* wl0 = W_lin + (size_t)o0 * H + kp * 4;
    const float* wl1 = W_lin + (size_t)o1 * H + kp * 4;
    #pragma unroll 4
    for (int j = 0; j < 32; ++j) {
      float4 h4 = *(const float4*)(hr + j * 32);     // fresh: post-inv L2
      float4 a4 = *(const float4*)(wl0 + j * 32);
      float4 c4 = *(const float4*)(wl1 + j * 32);
      f0 = fmaf(a4.x, h4.x, f0); f0 = fmaf(a4.y, h4.y, f0);
      f0 = fmaf(a4.z, h4.z, f0); f0 = fmaf(a4.w, h4.w, f0);
      f1 = fmaf(c4.x, h4.x, f1); f1 = fmaf(c4.y, h4.y, f1);
      f1 = fmaf(c4.z, h4.z, f1); f1 = fmaf(c4.w, h4.w, f1);
    }
    f0 += __shfl_xor(f0, 1, 64); f0 += __shfl_xor(f0, 2, 64); f0 += __shfl_xor(f0, 4, 64);
    f1 += __shfl_xor(f1, 1, 64); f1 += __shfl_xor(f1, 2, 64); f1 += __shfl_xor(f1, 4, 64);
    const float l0 = f0 + bl0, l1 = f1 + bl1;

    if (kp == 0) {
      const int boo = lane >> 3;
      lstash[boo * 17 + wv * 2]     = (t < pb_sl) ? l0 : 0.f;
      lstash[boo * 17 + wv * 2 + 1] = (t < pb_sl) ? l1 : 0.f;
      unsigned k0 = __float_as_uint(l0);
      k0 = (k0 & 0x80000000u) ? ~k0 : (k0 | 0x80000000u);
      unsigned k1 = __float_as_uint(l1);
      k1 = (k1 & 0x80000000u) ? ~k1 : (k1 | 0x80000000u);
      unsigned long long p0 = ((unsigned long long)k0 << 32) | (unsigned long long)(511 - o0);
      unsigned long long p1 = ((unsigned long long)k1 << 32) | (unsigned long long)(511 - o1);
      // reuse gp head as per-wave argmax scratch (safe: gp consumed pre-gbar)
      ((unsigned long long*)gp)[wv * 8 + boo] = (p0 > p1) ? p0 : p1;
    }
    __syncthreads();
    if (tid < 8) {
      unsigned long long m = ((unsigned long long*)gp)[tid];
      #pragma unroll
      for (int w = 1; w < 8; ++w) {
        unsigned long long v = ((unsigned long long*)gp)[w * 8 + tid];
        m = (v > m) ? v : m;
      }
      // reset the OTHER slot (read by all wave-7s at P1 of this step, which
      // provably precedes this point via gbar(t)); next written at t+2.
      if (og == 0)
        __hip_atomic_store(&amax[(size_t)((((t + 1) & 1) * 64) + bq * 8 + tid) * 8],
                           0ull, __ATOMIC_RELAXED, SCOPE_AGT);
      __hip_atomic_fetch_max(&amax[(size_t)(((t & 1) * 64) + bq * 8 + tid) * 8], m,
                             __ATOMIC_RELAXED, SCOPE_AGT);
    }
    if (tid == 0) {
      // wave 0: amax RMWs above are in THIS wave's vmcnt; drain, then count.
      asm volatile("s_waitcnt vmcnt(0)" ::: "memory");
      unsigned* dc = &sync[SY_DCNT(bid >> 4)];
      const unsigned a = __hip_atomic_fetch_add(dc, 1u, __ATOMIC_RELAXED, SCOPE_AGT);
      if ((a & 15u) == 15u) {
        const unsigned b = __hip_atomic_fetch_add(&sync[SY_DTOP], 1u,
                                                  __ATOMIC_RELAXED, SCOPE_AGT);
        if ((b & 15u) == 15u)
          __hip_atomic_store(&sync[SY_DFLAG], (unsigned)(t + 1),
                             __ATOMIC_RELAXED, SCOPE_AGT);
      }
    }
    if (tid < 128) {
      const int bb = tid >> 4, oj = tid & 15;
      // sc1 store: never dirty L2 (keeps buffer_inv safe)
      st4f_coh(&out[((size_t)(bq * 8 + bb) * T + t) * OO + og * 16 + oj],
               lstash[bb * 17 + oj]);
    }
    // no second device barrier: loop back to P1 (h_t already synced by gbar(t))
  }
}

extern "C" void kernel_launch(void* const* d_in, const int* in_sizes, int n_in,
                              void* d_out, int out_size, void* d_ws, size_t ws_size,
                              hipStream_t stream) {
  (void)in_sizes; (void)n_in; (void)out_size; (void)ws_size;
  const float* enc    = (const float*)d_in[0];
  const int*   slen   = (const int*)d_in[1];
  const float* W_ih   = (const float*)d_in[2];
  const float* W_hh   = (const float*)d_in[3];
  const float* b_ih   = (const float*)d_in[4];
  const float* b_hh   = (const float*)d_in[5];
  const float* W_lin  = (const float*)d_in[6];
  const float* b_lin  = (const float*)d_in[7];
  const float* emb    = (const float*)d_in[8];
  const float* init_t = (const float*)d_in[9];
  float* out = (float*)d_out;

  char* ws = (char*)d_ws;
  float*     hbuf  = (float*)(ws + WS_HBUF);
  _Float16*  h16hi = (_Float16*)(ws + WS_H16HI);
  _Float16*  h16lo = (_Float16*)(ws + WS_H16LO);
  _Float16*  e16hi = (_Float16*)(ws + WS_E16HI);
  _Float16*  e16lo = (_Float16*)(ws + WS_E16LO);
  unsigned long long* amax = (unsigned long long*)(ws + WS_AMAX);
  unsigned*  sync  = (unsigned*)(ws + WS_SYNC);
  unsigned*  zw    = (unsigned*)(ws + WS_AMAX);   // zero amax+sync region

  hipLaunchKernelGGL(init_kernel, dim3(512), dim3(256), 0, stream,
                     hbuf, h16hi, h16lo, e16hi, e16lo, emb, init_t, zw);
  hipLaunchKernelGGL(decode_kernel, dim3(NBLK), dim3(NTHR), 0, stream,
                     enc, slen, W_ih, W_hh, b_ih, b_hh, W_lin, b_lin,
                     out, hbuf, h16hi, h16lo, e16hi, e16lo, amax, sync);
}

// Round 5
// 17817.842 us; speedup vs baseline: 2.0855x; 1.1112x over previous
//
#include <hip/hip_runtime.h>
#include <math.h>

// Problem constants
#define B    64
#define T    512
#define D    1024
#define H    1024
#define E    128
#define OO   512

#define NBLK 256
#define NTHR 512

typedef _Float16 f16x8 __attribute__((ext_vector_type(8)));
typedef float    f32x4 __attribute__((ext_vector_type(4)));

// All MFMA inputs are scaled by 128 (f16 denormal floor dodge); gates get
// scaled back by 1/(128*128) at the cell update. Exact pow2 => no rounding.
#define SCALE      128.0f
#define INV_SCALE2 (1.0f / 16384.0f)

// ws byte layout (all 64B-aligned) — total 1,059,072 B (< proven 1.32 MB)
#define WS_HBUF   0          // fp32 [2][64][1024]   = 524288 B
#define WS_H16HI  524288     // f16  [2][64][1024]   = 262144 B (scaled x128)
#define WS_H16LO  786432     // f16  [2][64][1024]   = 262144 B
#define WS_AMAX   1048576    // u64, one per 64B line: idx=(parity*64+b)*8 -> 8192 B
#define WS_SYNC   1056768    // u32[576] sync words                        -> 2304 B
#define N_ZWORDS  ((8192 + 2304) / 4)   // amax + sync zero region, 2624 u32

// sync word indices (64B-padded lines)
#define SY_GCNT(g)  ((g) * 16)          // 16 groups, barrier arrivals
#define SY_DCNT(g)  (256 + (g) * 16)    // 16 groups, phase-B done arrivals
#define SY_GTOP     512
#define SY_GGEN     528
#define SY_DTOP     544
#define SY_DFLAG    560

#define SCOPE_AGT __HIP_MEMORY_SCOPE_AGENT

// Coherent (sc1, LLC-direct) stores — relaxed agent atomics bypass the
// non-coherent per-XCD L2 with NO wbl2/inv microcode. Producer side only;
// bulk reads are plain cached, made coherent by one buffer_inv per step.
__device__ __forceinline__ void st4f_coh(float* p, float v) {
  __hip_atomic_store(p, v, __ATOMIC_RELAXED, SCOPE_AGT);
}
__device__ __forceinline__ void st2h_coh(_Float16* p, _Float16 v) {
  union { _Float16 f; unsigned short u; } c; c.f = v;
  __hip_atomic_store((unsigned short*)p, c.u, __ATOMIC_RELAXED, SCOPE_AGT);
}

__global__ __launch_bounds__(256) void init_kernel(
    float* hbuf0, _Float16* h16hi, _Float16* h16lo, unsigned* zw) {
  const int i = blockIdx.x * 256 + threadIdx.x;  // 512 blocks -> 0..131071
  if (i < B * H) hbuf0[i] = 0.f;                 // h fp32 parity 0
  if (i < 2 * B * H) { h16hi[i] = (_Float16)0.f; h16lo[i] = (_Float16)0.f; }
  if (i < N_ZWORDS) zw[i] = 0u;                  // amax entries + all sync words
}

// Pure-relaxed poll: sc1 loads read the LLC directly every time.
__device__ __forceinline__ void poll_ge(unsigned* p, unsigned want) {
  for (;;) {
    const unsigned g = __hip_atomic_load(p, __ATOMIC_RELAXED, SCOPE_AGT);
    if (g >= want) break;
    __builtin_amdgcn_s_sleep(1);
  }
  asm volatile("" ::: "memory");   // compiler fence
}

// Split device barrier. Arrive: drain sc1 stores, block-sync, tid0 joins the
// 16x16 relaxed arrival tree. Wait: tid0 polls the generation flag, then ONE
// buffer_inv sc0 sc1 (safe: no kernel store ever dirties L2 — all global
// stores are sc1 write-through), block-sync.
__device__ __forceinline__ void gbar_arrive(unsigned* sync, int bid, unsigned q) {
  asm volatile("s_waitcnt vmcnt(0)" ::: "memory");  // my sc1 stores at LLC
  __syncthreads();
  if (threadIdx.x == 0) {
    unsigned* gc = &sync[SY_GCNT(bid >> 4)];
    const unsigned a = __hip_atomic_fetch_add(gc, 1u, __ATOMIC_RELAXED, SCOPE_AGT);
    if ((a & 15u) == 15u) {                       // last of my 16-group
      const unsigned b = __hip_atomic_fetch_add(&sync[SY_GTOP], 1u,
                                                __ATOMIC_RELAXED, SCOPE_AGT);
      if ((b & 15u) == 15u)                       // last group
        __hip_atomic_store(&sync[SY_GGEN], q + 1u, __ATOMIC_RELAXED, SCOPE_AGT);
    }
  }
}
__device__ __forceinline__ void gbar_wait(unsigned* sync, unsigned q) {
  if (threadIdx.x == 0) {
    poll_ge(&sync[SY_GGEN], q + 1u);
    asm volatile("buffer_inv sc0 sc1\n\ts_waitcnt vmcnt(0)" ::: "memory");
  }
  __syncthreads();
}

__device__ __forceinline__ float sigm(float x) { return 1.f / (1.f + expf(-x)); }

// fp32[8] -> scaled f16 hi/lo split
__device__ __forceinline__ void cvt8(const float* v, f16x8& hi, f16x8& lo) {
  #pragma unroll
  for (int j = 0; j < 8; ++j) {
    const float s = v[j] * SCALE;
    const _Float16 h = (_Float16)s;
    hi[j] = h;
    lo[j] = (_Float16)(s - (float)h);
  }
}

__global__ __launch_bounds__(NTHR, 2) void decode_kernel(
    const float* __restrict__ enc, const int* __restrict__ seq_lens,
    const float* __restrict__ W_ih, const float* __restrict__ W_hh,
    const float* __restrict__ b_ih, const float* __restrict__ b_hh,
    const float* __restrict__ W_lin, const float* __restrict__ b_lin,
    const float* __restrict__ emb, const float* __restrict__ init_t,
    float* __restrict__ out, float* __restrict__ hbuf,
    _Float16* __restrict__ h16hi, _Float16* __restrict__ h16lo,
    unsigned long long* __restrict__ amax, unsigned* __restrict__ sync) {

  // LDS: MFMA partials gp[8][16][66] + per-block G_emb slice + buffers
  __shared__ float    gp[8 * 16 * 66];     // 33792 B
  __shared__ _Float16 gemb[513 * 16];      // 16416 B: W_ie @ emb, this block's rows
  __shared__ int      idxbuf[64];          // per-batch label row (512 = init)
  __shared__ float    lstash[136];

  const int tid  = threadIdx.x;
  const int lane = tid & 63;
  const int wv   = tid >> 6;          // 0..7
  const int bid  = blockIdx.x;
  const int l15  = lane & 15;
  const int lq   = lane >> 4;         // quad 0..3

  // ---- MFMA identity: block owns 16 gate-rows (m = g*4+mi <-> r = g*H + bid*4+mi)
  const int am   = l15;
  const int arow = (am >> 2) * H + bid * 4 + (am & 3);
  // Uniform wave k-slice: wave wv owns x-tiles wv*4..wv*4+3 (K=1024 of enc)
  // and h-tiles wv*4..wv*4+3 (K=1024 of h). Emb handled via G_emb at cell.

  // ---- prologue 1: W -> scaled f16 hi/lo A-fragments, resident all steps ----
  f16x8 axhi[4], axlo[4], ahhi[4], ahlo[4];
  #pragma unroll
  for (int i = 0; i < 4; ++i) {
    const int kg = (wv * 4 + i) * 32 + lq * 8;   // 0..1023, 8-aligned
    float w8[8];
    const float* sx = W_ih + (size_t)arow * (D + E) + kg;
    *(float4*)(w8)     = *(const float4*)(sx);
    *(float4*)(w8 + 4) = *(const float4*)(sx + 4);
    cvt8(w8, axhi[i], axlo[i]);
    const float* sh = W_hh + (size_t)arow * H + kg;
    *(float4*)(w8)     = *(const float4*)(sh);
    *(float4*)(w8 + 4) = *(const float4*)(sh + 4);
    cvt8(w8, ahhi[i], ahlo[i]);
  }

  // ---- prologue 2: per-block G_emb slice -> LDS (gp as W_ie staging) ----
  // gemb[o*16 + e] = sum_k W_ih[r(e)][D+k] * emb_o[k], r(e)=(e>>2)*H+bid*4+(e&3)
  for (int idx = tid; idx < 16 * E; idx += NTHR) {
    const int e = idx >> 7, k = idx & 127;
    const int r = (e >> 2) * H + bid * 4 + (e & 3);
    gp[idx] = W_ih[(size_t)r * (D + E) + D + k];
  }
  if (tid < 64) idxbuf[tid] = 512;    // init_tensor row
  __syncthreads();
  for (int oi = tid; oi < 513 * 16; oi += NTHR) {
    const int o = oi >> 4, e = oi & 15;
    const float* ev = (o < OO) ? (emb + (size_t)o * E) : init_t;
    const float* wr = gp + e * 128;
    float s = 0.f;
    #pragma unroll 8
    for (int k = 0; k < E; k += 4) {
      const float4 e4 = *(const float4*)(ev + k);
      s += wr[k] * e4.x + wr[k + 1] * e4.y + wr[k + 2] * e4.z + wr[k + 3] * e4.w;
    }
    gemb[oi] = (_Float16)s;   // |s| ~ 0.01; f16 abs err ~3e-6, negligible
  }
  __syncthreads();

  // ---- cell-update identity: tid<256 owns (cmi, cb) ----
  const int cb  = tid & 63;
  const int cmi = tid >> 6;                        // valid when tid < 256
  const int csl = seq_lens[cb];
  float bias[4];
  if (tid < 256) {
    #pragma unroll
    for (int g = 0; g < 4; ++g) {
      const int r = g * H + bid * 4 + cmi;
      bias[g] = b_ih[r] + b_hh[r];
    }
  }
  const int sl_pre = (tid < 64) ? seq_lens[tid] : 0;

  // ---- phase B identity ----
  const int bq = bid >> 5, og = bid & 31;
  const int kp = lane & 7;
  const int pb_b  = bq * 8 + (lane >> 3);
  const int pb_sl = seq_lens[pb_b];
  const int o0 = og * 16 + wv * 2, o1 = o0 + 1;
  const float bl0 = b_lin[o0], bl1 = b_lin[o1];

  float c_reg = 0.f, h_reg = 0.f;

  // x-part of step tt's gates (enc only — no cross-block dependency)
  auto compute_accx = [&](int tt, f32x4* ax) {
    #pragma unroll
    for (int nt = 0; nt < 4; ++nt) {
      const int bb = nt * 16 + l15;
      const float* xrow = enc + ((size_t)bb * T + tt) * D;
      #pragma unroll
      for (int i = 0; i < 4; ++i) {
        const int kg = (wv * 4 + i) * 32 + lq * 8;
        float xv[8];
        *(float4*)(xv)     = *(const float4*)(xrow + kg);
        *(float4*)(xv + 4) = *(const float4*)(xrow + kg + 4);
        f16x8 bhi, blo;
        cvt8(xv, bhi, blo);
        ax[nt] = __builtin_amdgcn_mfma_f32_16x16x32_f16(axhi[i], bhi, ax[nt], 0, 0, 0);
        ax[nt] = __builtin_amdgcn_mfma_f32_16x16x32_f16(axlo[i], bhi, ax[nt], 0, 0, 0);
        ax[nt] = __builtin_amdgcn_mfma_f32_16x16x32_f16(axhi[i], blo, ax[nt], 0, 0, 0);
      }
    }
  };

  f32x4 accx[4] = {{0.f,0.f,0.f,0.f},{0.f,0.f,0.f,0.f},
                   {0.f,0.f,0.f,0.f},{0.f,0.f,0.f,0.f}};
  compute_accx(0, accx);              // pipeline prologue

  for (int t = 0; t < T; ++t) {
    // ---------- phase A-h: h-region MFMA on top of pipelined x-part ----------
    const int par0 = t & 1;
    f32x4 acc[4];
    #pragma unroll
    for (int nt = 0; nt < 4; ++nt) acc[nt] = accx[nt];
    #pragma unroll
    for (int nt = 0; nt < 4; ++nt) {
      const int bb = nt * 16 + l15;
      const _Float16* hhi = h16hi + (size_t)par0 * (B * H) + (size_t)bb * H;
      const _Float16* hlo = h16lo + (size_t)par0 * (B * H) + (size_t)bb * H;
      #pragma unroll
      for (int i = 0; i < 4; ++i) {
        const int kg = (wv * 4 + i) * 32 + lq * 8;
        f16x8 bhi = *(const f16x8*)(hhi + kg);   // fresh: post-inv L2
        f16x8 blo = *(const f16x8*)(hlo + kg);
        acc[nt] = __builtin_amdgcn_mfma_f32_16x16x32_f16(ahhi[i], bhi, acc[nt], 0, 0, 0);
        acc[nt] = __builtin_amdgcn_mfma_f32_16x16x32_f16(ahlo[i], bhi, acc[nt], 0, 0, 0);
        acc[nt] = __builtin_amdgcn_mfma_f32_16x16x32_f16(ahhi[i], blo, acc[nt], 0, 0, 0);
      }
    }

    // C-layout: col b = nt*16 + (lane&15), row m = quad*4 + reg
    {
      const int prow = lq * 4;
      #pragma unroll
      for (int nt = 0; nt < 4; ++nt) {
        const int pb = nt * 16 + l15;
        #pragma unroll
        for (int r = 0; r < 4; ++r)
          gp[(wv * 16 + prow + r) * 66 + pb] = acc[nt][r];
      }
    }

    // ---------- wave 0: feedback idx for THIS step (slack = all of A-h) ----------
    if (tid < 64 && t > 0) {
      if (lane == 0) poll_ge(&sync[SY_DFLAG], (unsigned)t);  // wave-wide stall
      asm volatile("" ::: "memory");
      if ((t - 1) < sl_pre) {
        const unsigned long long p = __hip_atomic_load(
            &amax[(size_t)((((t - 1) & 1) * 64) + tid) * 8],
            __ATOMIC_RELAXED, SCOPE_AGT);
        idxbuf[tid] = 511 - (int)(unsigned)(p & 0xffffffffu);
      }
    }
    __syncthreads();

    // ---------- cell update: partial sum + bias + G_emb[idx] (LDS) ----------
    if (tid < 256) {
      const _Float16* grow = gemb + idxbuf[cb] * 16 + cmi;
      float g4[4];
      #pragma unroll
      for (int g = 0; g < 4; ++g) {
        float s = 0.f;
        #pragma unroll
        for (int w = 0; w < 8; ++w) s += gp[(w * 16 + g * 4 + cmi) * 66 + cb];
        g4[g] = s * INV_SCALE2 + bias[g] + (float)grow[g * 4];
      }
      const float xi = sigm(g4[0]), xf = sigm(g4[1]);
      const float xg = tanhf(g4[2]), xo = sigm(g4[3]);
      const float cn = xf * c_reg + xi * xg;
      const float hn = xo * tanhf(cn);
      if (t < csl) { c_reg = cn; h_reg = hn; }
      const int par1 = (t + 1) & 1;
      const size_t hoff = (size_t)par1 * (B * H) + (size_t)cb * H + (bid * 4 + cmi);
      st4f_coh(&hbuf[hoff], h_reg);              // sc1: LLC write-through
      const float hs = h_reg * SCALE;
      const _Float16 hh = (_Float16)hs;
      st2h_coh(&h16hi[hoff], hh);
      st2h_coh(&h16lo[hoff], (_Float16)(hs - (float)hh));
    }

    gbar_arrive(sync, bid, (unsigned)t);

    // ---------- pipelined x-GEMM for t+1 hides the barrier propagation ----------
    #pragma unroll
    for (int nt = 0; nt < 4; ++nt) accx[nt] = (f32x4){0.f, 0.f, 0.f, 0.f};
    if (t + 1 < T) compute_accx(t + 1, accx);

    gbar_wait(sync, (unsigned)t);   // h_{t+1} visible; ONE L1/L2 inv

    // ---------- phase B: exact fp32 logits + argmax (plain cached loads) ----------
    float f0 = 0.f, f1 = 0.f;
    const float* hr  = hbuf + (size_t)((t + 1) & 1) * (B * H) + (size_t)pb_b * H + kp * 4;
    const float* wl0 = W_lin + (size_t)o0 * H + kp * 4;
    const float* wl1 = W_lin + (size_t)o1 * H + kp * 4;
    #pragma unroll 4
    for (int j = 0; j < 32; ++j) {
      float4 h4 = *(const float4*)(hr + j * 32);     // fresh: post-inv
      float4 a4 = *(const float4*)(wl0 + j * 32);
      float4 c4 = *(const float4*)(wl1 + j * 32);
      f0 = fmaf(a4.x, h4.x, f0); f0 = fmaf(a4.y, h4.y, f0);
      f0 = fmaf(a4.z, h4.z, f0); f0 = fmaf(a4.w, h4.w, f0);
      f1 = fmaf(c4.x, h4.x, f1); f1 = fmaf(c4.y, h4.y, f1);
      f1 = fmaf(c4.z, h4.z, f1); f1 = fmaf(c4.w, h4.w, f1);
    }
    f0 += __shfl_xor(f0, 1, 64); f0 += __shfl_xor(f0, 2, 64); f0 += __shfl_xor(f0, 4, 64);
    f1 += __shfl_xor(f1, 1, 64); f1 += __shfl_xor(f1, 2, 64); f1 += __shfl_xor(f1, 4, 64);
    const float l0 = f0 + bl0, l1 = f1 + bl1;

    if (kp == 0) {
      const int boo = lane >> 3;
      lstash[boo * 17 + wv * 2]     = (t < pb_sl) ? l0 : 0.f;
      lstash[boo * 17 + wv * 2 + 1] = (t < pb_sl) ? l1 : 0.f;
      unsigned k0 = __float_as_uint(l0);
      k0 = (k0 & 0x80000000u) ? ~k0 : (k0 | 0x80000000u);
      unsigned k1 = __float_as_uint(l1);
      k1 = (k1 & 0x80000000u) ? ~k1 : (k1 | 0x80000000u);
      unsigned long long p0 = ((unsigned long long)k0 << 32) | (unsigned long long)(511 - o0);
      unsigned long long p1 = ((unsigned long long)k1 << 32) | (unsigned long long)(511 - o1);
      // reuse gp head as per-wave argmax scratch (rows 0-1 = wave 0's region;
      // only wave 0 rewrites them next step, after its own reads)
      ((unsigned long long*)gp)[wv * 8 + boo] = (p0 > p1) ? p0 : p1;
    }
    __syncthreads();
    if (tid < 8) {
      unsigned long long m = ((unsigned long long*)gp)[tid];
      #pragma unroll
      for (int w = 1; w < 8; ++w) {
        unsigned long long v = ((unsigned long long*)gp)[w * 8 + tid];
        m = (v > m) ? v : m;
      }
      // reset the OTHER slot (all reads of it at feedback(t) precede gbar(t))
      if (og == 0)
        __hip_atomic_store(&amax[(size_t)((((t + 1) & 1) * 64) + bq * 8 + tid) * 8],
                           0ull, __ATOMIC_RELAXED, SCOPE_AGT);
      __hip_atomic_fetch_max(&amax[(size_t)(((t & 1) * 64) + bq * 8 + tid) * 8], m,
                             __ATOMIC_RELAXED, SCOPE_AGT);
    }
    if (tid == 0) {
      // amax RMWs above are in wave 0's vmcnt; drain, then done-chain.
      asm volatile("s_waitcnt vmcnt(0)" ::: "memory");
      unsigned* dc = &sync[SY_DCNT(bid >> 4)];
      const unsigned a = __hip_atomic_fetch_add(dc, 1u, __ATOMIC_RELAXED, SCOPE_AGT);
      if ((a & 15u) == 15u) {
        const unsigned b = __hip_atomic_fetch_add(&sync[SY_DTOP], 1u,
                                                  __ATOMIC_RELAXED, SCOPE_AGT);
        if ((b & 15u) == 15u)
          __hip_atomic_store(&sync[SY_DFLAG], (unsigned)(t + 1),
                             __ATOMIC_RELAXED, SCOPE_AGT);
      }
    }
    if (tid < 128) {
      const int bb = tid >> 4, oj = tid & 15;
      st4f_coh(&out[((size_t)(bq * 8 + bb) * T + t) * OO + og * 16 + oj],
               lstash[bb * 17 + oj]);             // sc1: never dirty L2
    }
  }
}

extern "C" void kernel_launch(void* const* d_in, const int* in_sizes, int n_in,
                              void* d_out, int out_size, void* d_ws, size_t ws_size,
                              hipStream_t stream) {
  (void)in_sizes; (void)n_in; (void)out_size; (void)ws_size;
  const float* enc    = (const float*)d_in[0];
  const int*   slen   = (const int*)d_in[1];
  const float* W_ih   = (const float*)d_in[2];
  const float* W_hh   = (const float*)d_in[3];
  const float* b_ih   = (const float*)d_in[4];
  const float* b_hh   = (const float*)d_in[5];
  const float* W_lin  = (const float*)d_in[6];
  const float* b_lin  = (const float*)d_in[7];
  const float* emb    = (const float*)d_in[8];
  const float* init_t = (const float*)d_in[9];
  float* out = (float*)d_out;

  char* ws = (char*)d_ws;
  float*     hbuf  = (float*)(ws + WS_HBUF);
  _Float16*  h16hi = (_Float16*)(ws + WS_H16HI);
  _Float16*  h16lo = (_Float16*)(ws + WS_H16LO);
  unsigned long long* amax = (unsigned long long*)(ws + WS_AMAX);
  unsigned*  sync  = (unsigned*)(ws + WS_SYNC);
  unsigned*  zw    = (unsigned*)(ws + WS_AMAX);   // zero amax+sync region

  hipLaunchKernelGGL(init_kernel, dim3(512), dim3(256), 0, stream,
                     hbuf, h16hi, h16lo, zw);
  hipLaunchKernelGGL(decode_kernel, dim3(NBLK), dim3(NTHR), 0, stream,
                     enc, slen, W_ih, W_hh, b_ih, b_hh, W_lin, b_lin,
                     emb, init_t, out, hbuf, h16hi, h16lo, amax, sync);
}

// Round 6
// 12389.775 us; speedup vs baseline: 2.9992x; 1.4381x over previous
//
#include <hip/hip_runtime.h>
#include <math.h>

// Problem constants
#define B    64
#define T    512
#define D    1024
#define H    1024
#define E    128
#define OO   512

#define NBLK 256
#define NTHR 512

typedef _Float16 f16x8 __attribute__((ext_vector_type(8)));
typedef float    f32x4 __attribute__((ext_vector_type(4)));

// All MFMA inputs are scaled by 128 (f16 denormal floor dodge); gates get
// scaled back by 1/(128*128) at the cell update. Exact pow2 => no rounding.
#define SCALE      128.0f
#define INV_SCALE2 (1.0f / 16384.0f)

// ws byte layout (all 64B-aligned) — total 1,059,072 B (< proven 1.32 MB)
#define WS_HBUF   0          // fp32 [2][64][1024]   = 524288 B
#define WS_H16HI  524288     // f16  [2][64][1024]   = 262144 B (scaled x128)
#define WS_H16LO  786432     // f16  [2][64][1024]   = 262144 B
#define WS_AMAX   1048576    // 64B line per (parity,batch): {u64 max, u32 count}
#define WS_SYNC   1056768    // u32[576] sync words
#define N_ZWORDS  ((8192 + 2304) / 4)   // amax + sync zero region, 2624 u32

// sync word indices (64B-padded lines)
#define SY_GCNT(g)  ((g) * 16)          // 16 groups, barrier arrivals
#define SY_GTOP     512
#define SY_GGEN     528

#define SCOPE_AGT __HIP_MEMORY_SCOPE_AGENT

// Coherent (sc1, LLC-direct) stores — relaxed agent atomics bypass the
// non-coherent per-XCD L2 with NO wbl2/inv microcode. Producer side only;
// bulk reads are plain cached, made coherent by one buffer_inv per step.
__device__ __forceinline__ void st4f_coh(float* p, float v) {
  __hip_atomic_store(p, v, __ATOMIC_RELAXED, SCOPE_AGT);
}
__device__ __forceinline__ void st2h_coh(_Float16* p, _Float16 v) {
  union { _Float16 f; unsigned short u; } c; c.f = v;
  __hip_atomic_store((unsigned short*)p, c.u, __ATOMIC_RELAXED, SCOPE_AGT);
}

__global__ __launch_bounds__(256) void init_kernel(
    float* hbuf0, _Float16* h16hi, _Float16* h16lo, unsigned* zw) {
  const int i = blockIdx.x * 256 + threadIdx.x;  // 512 blocks -> 0..131071
  if (i < B * H) hbuf0[i] = 0.f;                 // h fp32 parity 0
  if (i < 2 * B * H) { h16hi[i] = (_Float16)0.f; h16lo[i] = (_Float16)0.f; }
  if (i < N_ZWORDS) zw[i] = 0u;                  // amax lines + all sync words
}

// Pure-relaxed poll: sc1 loads read the LLC directly every time.
__device__ __forceinline__ void poll_ge(unsigned* p, unsigned want) {
  for (;;) {
    const unsigned g = __hip_atomic_load(p, __ATOMIC_RELAXED, SCOPE_AGT);
    if (g >= want) break;
    __builtin_amdgcn_s_sleep(1);
  }
  asm volatile("" ::: "memory");   // compiler fence
}

// Split device barrier. Arrive: drain sc1 stores, block-sync, tid0 joins the
// 16x16 relaxed arrival tree. Wait: tid0 polls the generation flag, then ONE
// buffer_inv sc0 sc1 (safe: no kernel store ever dirties L2 — all global
// stores are sc1 write-through), block-sync.
__device__ __forceinline__ void gbar_arrive(unsigned* sync, int bid, unsigned q) {
  asm volatile("s_waitcnt vmcnt(0)" ::: "memory");  // my sc1 stores at LLC
  __syncthreads();
  if (threadIdx.x == 0) {
    unsigned* gc = &sync[SY_GCNT(bid >> 4)];
    const unsigned a = __hip_atomic_fetch_add(gc, 1u, __ATOMIC_RELAXED, SCOPE_AGT);
    if ((a & 15u) == 15u) {                       // last of my 16-group
      const unsigned b = __hip_atomic_fetch_add(&sync[SY_GTOP], 1u,
                                                __ATOMIC_RELAXED, SCOPE_AGT);
      if ((b & 15u) == 15u)                       // last group
        __hip_atomic_store(&sync[SY_GGEN], q + 1u, __ATOMIC_RELAXED, SCOPE_AGT);
    }
  }
}
__device__ __forceinline__ void gbar_wait(unsigned* sync, unsigned q) {
  if (threadIdx.x == 0) {
    poll_ge(&sync[SY_GGEN], q + 1u);
    asm volatile("buffer_inv sc0 sc1\n\ts_waitcnt vmcnt(0)" ::: "memory");
  }
  __syncthreads();
}

__device__ __forceinline__ float sigm(float x) { return 1.f / (1.f + expf(-x)); }

// fp32[8] -> scaled f16 hi/lo split
__device__ __forceinline__ void cvt8(const float* v, f16x8& hi, f16x8& lo) {
  #pragma unroll
  for (int j = 0; j < 8; ++j) {
    const float s = v[j] * SCALE;
    const _Float16 h = (_Float16)s;
    hi[j] = h;
    lo[j] = (_Float16)(s - (float)h);
  }
}

__global__ __launch_bounds__(NTHR, 2) void decode_kernel(
    const float* __restrict__ enc, const int* __restrict__ seq_lens,
    const float* __restrict__ W_ih, const float* __restrict__ W_hh,
    const float* __restrict__ b_ih, const float* __restrict__ b_hh,
    const float* __restrict__ W_lin, const float* __restrict__ b_lin,
    const float* __restrict__ emb, const float* __restrict__ init_t,
    float* __restrict__ out, float* __restrict__ hbuf,
    _Float16* __restrict__ h16hi, _Float16* __restrict__ h16lo,
    unsigned long long* __restrict__ amax, unsigned* __restrict__ sync) {

  // LDS: MFMA partials + W_lin slice (inv-proof) + transposed G_emb + buffers
  __shared__ float    gp[8 * 16 * 66];     // 33792 B
  __shared__ float    wlds[16 * 1024];     // 65536 B: W_lin rows og*16..+15
  __shared__ _Float16 gemb[16 * 520];      // 16640 B: [e][o], stride 520
  __shared__ int      idxbuf[64];          // per-batch label row (512 = init)
  __shared__ float    lstash[136];

  const int tid  = threadIdx.x;
  const int lane = tid & 63;
  const int wv   = tid >> 6;          // 0..7
  const int bid  = blockIdx.x;
  const int l15  = lane & 15;
  const int lq   = lane >> 4;         // quad 0..3

  // ---- MFMA identity: block owns 16 gate-rows (m = g*4+mi <-> r = g*H + bid*4+mi)
  const int am   = l15;
  const int arow = (am >> 2) * H + bid * 4 + (am & 3);

  // ---- prologue 1: W -> scaled f16 hi/lo A-fragments, resident all steps ----
  f16x8 axhi[4], axlo[4], ahhi[4], ahlo[4];
  #pragma unroll
  for (int i = 0; i < 4; ++i) {
    const int kg = (wv * 4 + i) * 32 + lq * 8;   // 0..1023, 8-aligned
    float w8[8];
    const float* sx = W_ih + (size_t)arow * (D + E) + kg;
    *(float4*)(w8)     = *(const float4*)(sx);
    *(float4*)(w8 + 4) = *(const float4*)(sx + 4);
    cvt8(w8, axhi[i], axlo[i]);
    const float* sh = W_hh + (size_t)arow * H + kg;
    *(float4*)(w8)     = *(const float4*)(sh);
    *(float4*)(w8 + 4) = *(const float4*)(sh + 4);
    cvt8(w8, ahhi[i], ahlo[i]);
  }

  // ---- phase B identity (needed for W_lin staging) ----
  const int bq = bid >> 5, og = bid & 31;
  const int kp = lane & 7;
  const int pb_b  = bq * 8 + (lane >> 3);
  const int pb_sl = seq_lens[pb_b];
  const int o0 = og * 16 + wv * 2, o1 = o0 + 1;
  const float bl0 = b_lin[o0], bl1 = b_lin[o1];

  // ---- prologue 2: W_lin slice -> LDS (64 KB, survives buffer_inv) ----
  for (int i4 = tid; i4 < 16 * 256; i4 += NTHR) {   // 4096 float4s
    const int row = i4 >> 8, c4 = i4 & 255;
    *(float4*)&wlds[row * 1024 + c4 * 4] =
        *(const float4*)(W_lin + (size_t)(og * 16 + row) * H + c4 * 4);
  }

  // ---- prologue 3: per-block G_emb slice -> LDS, TRANSPOSED [e][o] ----
  // gemb[e*520 + o] = sum_k W_ih[r(e)][D+k] * emb_o[k], r(e)=(e>>2)*H+bid*4+(e&3)
  for (int idx = tid; idx < 16 * E; idx += NTHR) {
    const int e = idx >> 7, k = idx & 127;
    const int r = (e >> 2) * H + bid * 4 + (e & 3);
    gp[idx] = W_ih[(size_t)r * (D + E) + D + k];
  }
  if (tid < 64) idxbuf[tid] = 512;    // init_tensor row
  __syncthreads();
  for (int oi = tid; oi < 513 * 16; oi += NTHR) {
    const int o = oi >> 4, e = oi & 15;
    const float* ev = (o < OO) ? (emb + (size_t)o * E) : init_t;
    const float* wr = gp + e * 128;
    float s = 0.f;
    #pragma unroll 8
    for (int k = 0; k < E; k += 4) {
      const float4 e4 = *(const float4*)(ev + k);
      s += wr[k] * e4.x + wr[k + 1] * e4.y + wr[k + 2] * e4.z + wr[k + 3] * e4.w;
    }
    gemb[e * 520 + o] = (_Float16)s;   // |s| ~ 0.01; f16 abs err ~3e-6
  }
  __syncthreads();

  // ---- cell-update identity: tid<256 owns (cmi, cb) ----
  const int cb  = tid & 63;
  const int cmi = tid >> 6;                        // valid when tid < 256
  const int csl = seq_lens[cb];
  float bias[4];
  if (tid < 256) {
    #pragma unroll
    for (int g = 0; g < 4; ++g) {
      const int r = g * H + bid * 4 + cmi;
      bias[g] = b_ih[r] + b_hh[r];
    }
  }
  const int sl_pre = (tid < 64) ? seq_lens[tid] : 0;

  float c_reg = 0.f, h_reg = 0.f;

  // x-part of step tt's gates (enc only — no cross-block dependency)
  auto compute_accx = [&](int tt, f32x4* ax) {
    #pragma unroll
    for (int nt = 0; nt < 4; ++nt) {
      const int bb = nt * 16 + l15;
      const float* xrow = enc + ((size_t)bb * T + tt) * D;
      #pragma unroll
      for (int i = 0; i < 4; ++i) {
        const int kg = (wv * 4 + i) * 32 + lq * 8;
        float xv[8];
        *(float4*)(xv)     = *(const float4*)(xrow + kg);
        *(float4*)(xv + 4) = *(const float4*)(xrow + kg + 4);
        f16x8 bhi, blo;
        cvt8(xv, bhi, blo);
        ax[nt] = __builtin_amdgcn_mfma_f32_16x16x32_f16(axhi[i], bhi, ax[nt], 0, 0, 0);
        ax[nt] = __builtin_amdgcn_mfma_f32_16x16x32_f16(axlo[i], bhi, ax[nt], 0, 0, 0);
        ax[nt] = __builtin_amdgcn_mfma_f32_16x16x32_f16(axhi[i], blo, ax[nt], 0, 0, 0);
      }
    }
  };

  f32x4 accx[4] = {{0.f,0.f,0.f,0.f},{0.f,0.f,0.f,0.f},
                   {0.f,0.f,0.f,0.f},{0.f,0.f,0.f,0.f}};
  compute_accx(0, accx);              // pipeline prologue

  for (int t = 0; t < T; ++t) {
    // ---------- phase A-h: h-region MFMA on top of pipelined x-part ----------
    const int par0 = t & 1;
    f32x4 acc[4];
    #pragma unroll
    for (int nt = 0; nt < 4; ++nt) acc[nt] = accx[nt];
    #pragma unroll
    for (int nt = 0; nt < 4; ++nt) {
      const int bb = nt * 16 + l15;
      const _Float16* hhi = h16hi + (size_t)par0 * (B * H) + (size_t)bb * H;
      const _Float16* hlo = h16lo + (size_t)par0 * (B * H) + (size_t)bb * H;
      #pragma unroll
      for (int i = 0; i < 4; ++i) {
        const int kg = (wv * 4 + i) * 32 + lq * 8;
        f16x8 bhi = *(const f16x8*)(hhi + kg);   // fresh: post-inv L2
        f16x8 blo = *(const f16x8*)(hlo + kg);
        acc[nt] = __builtin_amdgcn_mfma_f32_16x16x32_f16(ahhi[i], bhi, acc[nt], 0, 0, 0);
        acc[nt] = __builtin_amdgcn_mfma_f32_16x16x32_f16(ahlo[i], bhi, acc[nt], 0, 0, 0);
        acc[nt] = __builtin_amdgcn_mfma_f32_16x16x32_f16(ahhi[i], blo, acc[nt], 0, 0, 0);
      }
    }

    // C-layout: col b = nt*16 + (lane&15), row m = quad*4 + reg
    {
      const int prow = lq * 4;
      #pragma unroll
      for (int nt = 0; nt < 4; ++nt) {
        const int pb = nt * 16 + l15;
        #pragma unroll
        for (int r = 0; r < 4; ++r)
          gp[(wv * 16 + prow + r) * 66 + pb] = acc[nt][r];
      }
    }

    // ---------- wave 0: feedback idx via per-line completion counts ----------
    // count==32 on a 64B amax line  =>  all 32 quadrant blocks' fetch_max are
    // at the LLC (each contributor drains vmcnt between max and count-add,
    // and the LLC serializes ops per line) => max word is final.
    if (tid < 64 && t > 0) {
      const unsigned long long* line =
          &amax[(size_t)((((t - 1) & 1) * 64) + tid) * 8];
      for (;;) {
        const unsigned cnt = __hip_atomic_load((const unsigned*)line + 2,
                                               __ATOMIC_RELAXED, SCOPE_AGT);
        if (__all(cnt == 32u)) break;
        __builtin_amdgcn_s_sleep(1);
      }
      asm volatile("" ::: "memory");
      if ((t - 1) < sl_pre) {
        const unsigned long long p =
            __hip_atomic_load(line, __ATOMIC_RELAXED, SCOPE_AGT);
        idxbuf[tid] = 511 - (int)(unsigned)(p & 0xffffffffu);
      }
    }
    __syncthreads();

    // ---------- cell update: partial sum + bias + G_emb[e][idx] (LDS) ----------
    if (tid < 256) {
      const int eidx = idxbuf[cb];
      float g4[4];
      #pragma unroll
      for (int g = 0; g < 4; ++g) {
        float s = 0.f;
        #pragma unroll
        for (int w = 0; w < 8; ++w) s += gp[(w * 16 + g * 4 + cmi) * 66 + cb];
        g4[g] = s * INV_SCALE2 + bias[g] + (float)gemb[(g * 4 + cmi) * 520 + eidx];
      }
      const float xi = sigm(g4[0]), xf = sigm(g4[1]);
      const float xg = tanhf(g4[2]), xo = sigm(g4[3]);
      const float cn = xf * c_reg + xi * xg;
      const float hn = xo * tanhf(cn);
      if (t < csl) { c_reg = cn; h_reg = hn; }
      const int par1 = (t + 1) & 1;
      const size_t hoff = (size_t)par1 * (B * H) + (size_t)cb * H + (bid * 4 + cmi);
      st4f_coh(&hbuf[hoff], h_reg);              // sc1: LLC write-through
      const float hs = h_reg * SCALE;
      const _Float16 hh = (_Float16)hs;
      st2h_coh(&h16hi[hoff], hh);
      st2h_coh(&h16lo[hoff], (_Float16)(hs - (float)hh));
    }

    gbar_arrive(sync, bid, (unsigned)t);

    // ---------- pipelined x-GEMM for t+1 hides the barrier propagation ----------
    #pragma unroll
    for (int nt = 0; nt < 4; ++nt) accx[nt] = (f32x4){0.f, 0.f, 0.f, 0.f};
    if (t + 1 < T) compute_accx(t + 1, accx);

    gbar_wait(sync, (unsigned)t);   // h_{t+1} visible; ONE L1/L2 inv

    // ---------- phase B: logits from LDS W_lin + fresh hbuf; argmax publish ----
    float f0 = 0.f, f1 = 0.f;
    const float* hr  = hbuf + (size_t)((t + 1) & 1) * (B * H) + (size_t)pb_b * H + kp * 4;
    const float* wl0 = wlds + (size_t)(wv * 2) * 1024 + kp * 4;       // LDS
    const float* wl1 = wlds + (size_t)(wv * 2 + 1) * 1024 + kp * 4;   // LDS
    #pragma unroll 4
    for (int j = 0; j < 32; ++j) {
      float4 h4 = *(const float4*)(hr + j * 32);     // fresh: post-inv
      float4 a4 = *(const float4*)(wl0 + j * 32);    // ds_read_b128, conflict-free
      float4 c4 = *(const float4*)(wl1 + j * 32);
      f0 = fmaf(a4.x, h4.x, f0); f0 = fmaf(a4.y, h4.y, f0);
      f0 = fmaf(a4.z, h4.z, f0); f0 = fmaf(a4.w, h4.w, f0);
      f1 = fmaf(c4.x, h4.x, f1); f1 = fmaf(c4.y, h4.y, f1);
      f1 = fmaf(c4.z, h4.z, f1); f1 = fmaf(c4.w, h4.w, f1);
    }
    f0 += __shfl_xor(f0, 1, 64); f0 += __shfl_xor(f0, 2, 64); f0 += __shfl_xor(f0, 4, 64);
    f1 += __shfl_xor(f1, 1, 64); f1 += __shfl_xor(f1, 2, 64); f1 += __shfl_xor(f1, 4, 64);
    const float l0 = f0 + bl0, l1 = f1 + bl1;

    if (kp == 0) {
      const int boo = lane >> 3;
      lstash[boo * 17 + wv * 2]     = (t < pb_sl) ? l0 : 0.f;
      lstash[boo * 17 + wv * 2 + 1] = (t < pb_sl) ? l1 : 0.f;
      unsigned k0 = __float_as_uint(l0);
      k0 = (k0 & 0x80000000u) ? ~k0 : (k0 | 0x80000000u);
      unsigned k1 = __float_as_uint(l1);
      k1 = (k1 & 0x80000000u) ? ~k1 : (k1 | 0x80000000u);
      unsigned long long p0 = ((unsigned long long)k0 << 32) | (unsigned long long)(511 - o0);
      unsigned long long p1 = ((unsigned long long)k1 << 32) | (unsigned long long)(511 - o1);
      // reuse gp head as per-wave argmax scratch (safe: gp consumed pre-gbar)
      ((unsigned long long*)gp)[wv * 8 + boo] = (p0 > p1) ? p0 : p1;
    }
    __syncthreads();
    if (tid < 8) {
      unsigned long long m = ((unsigned long long*)gp)[tid];
      #pragma unroll
      for (int w = 1; w < 8; ++w) {
        unsigned long long v = ((unsigned long long*)gp)[w * 8 + tid];
        m = (v > m) ? v : m;
      }
      unsigned long long* line = &amax[(size_t)(((t & 1) * 64) + bq * 8 + tid) * 8];
      __hip_atomic_fetch_max(line, m, __ATOMIC_RELAXED, SCOPE_AGT);
      // drain: my max is at the LLC before my count-add lands on the same line
      asm volatile("s_waitcnt vmcnt(0)" ::: "memory");
      __hip_atomic_fetch_add((unsigned*)line + 2, 1u, __ATOMIC_RELAXED, SCOPE_AGT);
      // reset the OTHER slot (all reads of it at feedback(t) precede gbar(t);
      // all publishes to it from B(t-1) drained at arrive(t))
      if (og == 0) {
        unsigned long long* oline =
            &amax[(size_t)((((t + 1) & 1) * 64) + bq * 8 + tid) * 8];
        __hip_atomic_store(oline, 0ull, __ATOMIC_RELAXED, SCOPE_AGT);
        __hip_atomic_store((unsigned*)oline + 2, 0u, __ATOMIC_RELAXED, SCOPE_AGT);
      }
    }
    if (tid < 128) {
      const int bb = tid >> 4, oj = tid & 15;
      st4f_coh(&out[((size_t)(bq * 8 + bb) * T + t) * OO + og * 16 + oj],
               lstash[bb * 17 + oj]);             // sc1: never dirty L2
    }
  }
}

extern "C" void kernel_launch(void* const* d_in, const int* in_sizes, int n_in,
                              void* d_out, int out_size, void* d_ws, size_t ws_size,
                              hipStream_t stream) {
  (void)in_sizes; (void)n_in; (void)out_size; (void)ws_size;
  const float* enc    = (const float*)d_in[0];
  const int*   slen   = (const int*)d_in[1];
  const float* W_ih   = (const float*)d_in[2];
  const float* W_hh   = (const float*)d_in[3];
  const float* b_ih   = (const float*)d_in[4];
  const float* b_hh   = (const float*)d_in[5];
  const float* W_lin  = (const float*)d_in[6];
  const float* b_lin  = (const float*)d_in[7];
  const float* emb    = (const float*)d_in[8];
  const float* init_t = (const float*)d_in[9];
  float* out = (float*)d_out;

  char* ws = (char*)d_ws;
  float*     hbuf  = (float*)(ws + WS_HBUF);
  _Float16*  h16hi = (_Float16*)(ws + WS_H16HI);
  _Float16*  h16lo = (_Float16*)(ws + WS_H16LO);
  unsigned long long* amax = (unsigned long long*)(ws + WS_AMAX);
  unsigned*  sync  = (unsigned*)(ws + WS_SYNC);
  unsigned*  zw    = (unsigned*)(ws + WS_AMAX);   // zero amax+sync region

  hipLaunchKernelGGL(init_kernel, dim3(512), dim3(256), 0, stream,
                     hbuf, h16hi, h16lo, zw);
  hipLaunchKernelGGL(decode_kernel, dim3(NBLK), dim3(NTHR), 0, stream,
                     enc, slen, W_ih, W_hh, b_ih, b_hh, W_lin, b_lin,
                     emb, init_t, out, hbuf, h16hi, h16lo, amax, sync);
}